// Round 1
// baseline (1049.010 us; speedup 1.0000x reference)
//
#include <hip/hip_runtime.h>

// Problem constants (fixed by reference)
#define NN 50000      // nodes
#define NE 800000     // edges
#define DD 256        // node feat dim
#define GFEAT 200     // graph feat dim
#define NG 512        // graphs

typedef __bf16 bf16;
typedef bf16 bf16x4 __attribute__((ext_vector_type(4)));
typedef bf16 bf16x8 __attribute__((ext_vector_type(8)));
typedef float f32x4 __attribute__((ext_vector_type(4)));

// async global->LDS, 16B per lane. HW dest = wave-uniform base + lane*16.
__device__ __forceinline__ void gl_lds16(const bf16* g, bf16* l) {
    __builtin_amdgcn_global_load_lds(
        (const __attribute__((address_space(1))) uint32_t*)(g),
        (__attribute__((address_space(3))) uint32_t*)(l), 16, 0, 0);
}

// swizzled fragment read: LDS [row][32k] where chunk c holds global chunk c^((row>>1)&3)
__device__ __forceinline__ bf16x8 frag_ld(const bf16* s, int R, int C) {
    return *(const bf16x8*)&s[R * 32 + ((C ^ ((R >> 1) & 3)) << 3)];
}

#define EPI_STRIDE 136   // bf16 elems; 272 B row stride (16B-aligned, bank-shift 4/row)

// ---------------------------------------------------------------------------
// conversions
// ---------------------------------------------------------------------------
__global__ __launch_bounds__(256) void conv_x2_kernel(const float* __restrict__ in0,
                                                      const float* __restrict__ in1,
                                                      bf16* __restrict__ out0,
                                                      bf16* __restrict__ out1, int n4) {
    const float* in = blockIdx.y ? in1 : in0;
    bf16* out = blockIdx.y ? out1 : out0;
    int i = blockIdx.x * 256 + threadIdx.x;
    if (i < n4) {
        float4 v = ((const float4*)in)[i];
        bf16x4 o;
        o[0] = (bf16)v.x; o[1] = (bf16)v.y; o[2] = (bf16)v.z; o[3] = (bf16)v.w;
        ((bf16x4*)out)[i] = o;
    }
}

// 8 weight matrices fp32 [K][N] -> bf16 [256][256] = [n][k] transposed, zero-padded.
__global__ __launch_bounds__(256) void conv_w8_kernel(
    const float* __restrict__ w0, const float* __restrict__ w1,
    const float* __restrict__ w2, const float* __restrict__ w3,
    const float* __restrict__ w4, const float* __restrict__ w5,
    const float* __restrict__ w6, const float* __restrict__ w7,
    bf16* __restrict__ out_base) {
    const float* ws[8] = {w0, w1, w2, w3, w4, w5, w6, w7};
    const int Ns[8] = {DD, DD, DD, GFEAT, DD, DD, DD, GFEAT};
    int m = blockIdx.y;
    const float* in = ws[m];
    int N = Ns[m];
    int idx = blockIdx.x * 256 + threadIdx.x;   // 0..65535 over [n][k]
    int n = idx >> 8, k = idx & 255;
    float v = (n < N) ? in[k * N + n] : 0.f;
    out_base[(size_t)m * 65536 + idx] = (bf16)v;
}

// ---------------------------------------------------------------------------
// CSR build, atomic-free at global scope: bucketed LDS counting sort.
// 128 buckets/branch x 391 nodes/bucket (128*391 = 50048 >= 50000).
// Each block streams the full dst[] (3.2 MB, L2-resident; all blocks co-paced)
// and bins only its bucket's edges via LDS hist / LDS cursors.
// ---------------------------------------------------------------------------
#define NB_B 128
#define NPB  391

// Pass 1: per-bucket LDS histogram -> local exclusive offsets (into offs[]) +
// bucket totals. grid (NB_B, 2), 512 threads.
__global__ __launch_bounds__(512) void csr_hist_kernel(
    const int* __restrict__ d0, const int* __restrict__ d1,
    int* __restrict__ offs0, int* __restrict__ offs1,
    int* __restrict__ bt0, int* __restrict__ bt1) {
    const int b = blockIdx.x, t = threadIdx.x;
    const int* dst = blockIdx.y ? d1 : d0;
    int* offs = blockIdx.y ? offs1 : offs0;
    int* bt = blockIdx.y ? bt1 : bt0;
    const int lo = b * NPB;
    const int cnt = (NN - lo < NPB) ? (NN - lo) : NPB;

    __shared__ int hist[NPB];
    __shared__ int s[512];
    if (t < NPB) hist[t] = 0;
    __syncthreads();

    const int4* d4 = (const int4*)dst;
#pragma unroll 4
    for (int i = t; i < NE / 4; i += 512) {
        int4 v = d4[i];
        if ((unsigned)(v.x - lo) < (unsigned)cnt) atomicAdd(&hist[v.x - lo], 1);
        if ((unsigned)(v.y - lo) < (unsigned)cnt) atomicAdd(&hist[v.y - lo], 1);
        if ((unsigned)(v.z - lo) < (unsigned)cnt) atomicAdd(&hist[v.z - lo], 1);
        if ((unsigned)(v.w - lo) < (unsigned)cnt) atomicAdd(&hist[v.w - lo], 1);
    }
    __syncthreads();

    // inclusive scan of hist (padded to 512) -> local exclusive prefix
    int h = (t < NPB) ? hist[t] : 0;
    s[t] = h;
    __syncthreads();
    for (int off = 1; off < 512; off <<= 1) {
        int a = (t >= off) ? s[t - off] : 0;
        __syncthreads();
        s[t] += a;
        __syncthreads();
    }
    if (t < cnt) offs[lo + t] = s[t] - h;       // bucket-local exclusive offset
    if (t == 0) bt[b] = s[NPB - 1];             // bucket total
}

// Pass 1.5: exclusive scan of 128 bucket totals (in place). grid (1,2), 128 thr.
__global__ __launch_bounds__(128) void csr_bases_kernel(
    int* __restrict__ bt0, int* __restrict__ bt1,
    int* __restrict__ offs0, int* __restrict__ offs1) {
    const int t = threadIdx.x;
    int* bt = blockIdx.y ? bt1 : bt0;
    __shared__ int s[128];
    int v = bt[t];
    s[t] = v;
    __syncthreads();
    for (int off = 1; off < 128; off <<= 1) {
        int a = (t >= off) ? s[t - off] : 0;
        __syncthreads();
        s[t] += a;
        __syncthreads();
    }
    bt[t] = s[t] - v;                           // exclusive bucket base
    if (t == 0) (blockIdx.y ? offs1 : offs0)[NN] = NE;
}

// Pass 2: finalize offs (local + base), scatter src into csr via LDS cursors.
// Writes land in the bucket's contiguous CSR region. grid (NB_B, 2), 512 thr.
__global__ __launch_bounds__(512) void csr_scatter_kernel(
    const int* __restrict__ sA, const int* __restrict__ sB,
    const int* __restrict__ d0, const int* __restrict__ d1,
    int* __restrict__ offs0, int* __restrict__ offs1,
    const int* __restrict__ bt0, const int* __restrict__ bt1,
    int* __restrict__ csr0, int* __restrict__ csr1) {
    const int b = blockIdx.x, t = threadIdx.x;
    const int* src = blockIdx.y ? sB : sA;
    const int* dst = blockIdx.y ? d1 : d0;
    int* offs = blockIdx.y ? offs1 : offs0;
    const int* bt = blockIdx.y ? bt1 : bt0;
    int* csr = blockIdx.y ? csr1 : csr0;
    const int lo = b * NPB;
    const int cnt = (NN - lo < NPB) ? (NN - lo) : NPB;

    __shared__ int cur[NPB];
    const int base = bt[b];
    if (t < cnt) {
        int f = offs[lo + t] + base;
        offs[lo + t] = f;                       // final global offset
        cur[t] = f;
    }
    __syncthreads();

    const int4* d4 = (const int4*)dst;
#pragma unroll 4
    for (int i = t; i < NE / 4; i += 512) {
        int4 v = d4[i];
        int e = i * 4;
        if ((unsigned)(v.x - lo) < (unsigned)cnt) csr[atomicAdd(&cur[v.x - lo], 1)] = src[e];
        if ((unsigned)(v.y - lo) < (unsigned)cnt) csr[atomicAdd(&cur[v.y - lo], 1)] = src[e + 1];
        if ((unsigned)(v.z - lo) < (unsigned)cnt) csr[atomicAdd(&cur[v.z - lo], 1)] = src[e + 2];
        if ((unsigned)(v.w - lo) < (unsigned)cnt) csr[atomicAdd(&cur[v.w - lo], 1)] = src[e + 3];
    }
}

// ---------------------------------------------------------------------------
// bf16 MFMA GEMM (generic, bf16 out, storage width outW=256):
// C[M,0..N) = A[M,K] @ Bt[N,K]^T (+bias on cols<Nb) (+relu)
// 128x128 tile, BK=32, 256 threads (4 waves 2x2), swizzled LDS, LDS epilogue.
// ---------------------------------------------------------------------------
__global__ __launch_bounds__(256) void mfma_gemm_kernel(
    const bf16* __restrict__ A, const bf16* __restrict__ Bt,
    const float* __restrict__ bias, bf16* __restrict__ out,
    int M, int K, int Nb, int do_relu) {
    __shared__ bf16 smem[16384];     // As | Bs during K-loop; epilogue buffer after
    bf16* As = smem;
    bf16* Bs = smem + 8192;

    const int t    = threadIdx.x;
    const int lane = t & 63;
    const int w    = t >> 6;
    const int row0 = blockIdx.y * 128;
    const int col0 = blockIdx.x * 128;

    f32x4 acc[4][4] = {};
    const int wm = (w >> 1) * 64, wn = (w & 1) * 64;
    const int fm = lane & 15, fC = lane >> 4;

    for (int k0 = 0; k0 < K; k0 += 32) {
#pragma unroll
        for (int r = 0; r < 2; r++) {
            int flat = r * 256 + t;
            int fr = flat >> 2, fc = flat & 3;
            int fcg = fc ^ ((fr >> 1) & 3);          // swizzle
            int arow = row0 + fr;
            if (arow > M - 1) arow = M - 1;
            gl_lds16(&A[(size_t)arow * K + k0 + fcg * 8], &As[flat * 8]);
        }
#pragma unroll
        for (int r = 0; r < 2; r++) {
            int flat = r * 256 + t;
            int fr = flat >> 2, fc = flat & 3;
            int fcg = fc ^ ((fr >> 1) & 3);
            int brow = col0 + fr;                    // Bt padded
            gl_lds16(&Bt[(size_t)brow * K + k0 + fcg * 8], &Bs[flat * 8]);
        }
        __syncthreads();

        bf16x8 af[4], bfr[4];
#pragma unroll
        for (int i = 0; i < 4; i++) af[i] = frag_ld(As, wm + i * 16 + fm, fC);
#pragma unroll
        for (int i = 0; i < 4; i++) bfr[i] = frag_ld(Bs, wn + i * 16 + fm, fC);
#pragma unroll
        for (int i = 0; i < 4; i++)
#pragma unroll
            for (int j = 0; j < 4; j++)
                acc[i][j] = __builtin_amdgcn_mfma_f32_16x16x32_bf16(af[i], bfr[j], acc[i][j], 0, 0, 0);
        __syncthreads();
    }

    // bias per j (cols wn+fm+j*16)
    float bv[4];
#pragma unroll
    for (int j = 0; j < 4; j++) {
        int col = col0 + wn + fm + j * 16;
        bv[j] = (bias && col < Nb) ? bias[col] : 0.f;
    }

    // epilogue: 2 passes of 64 rows through LDS, then 16B coalesced stores
#pragma unroll
    for (int p = 0; p < 2; p++) {
        if ((w >> 1) == p) {
#pragma unroll
            for (int i = 0; i < 4; i++)
#pragma unroll
                for (int j = 0; j < 4; j++)
#pragma unroll
                    for (int r2 = 0; r2 < 4; r2++) {
                        int rl = i * 16 + (lane >> 4) * 4 + r2;   // 0..63
                        int cl = wn + fm + j * 16;                // 0..127
                        float v = acc[i][j][r2] + bv[j];
                        if (do_relu) v = fmaxf(v, 0.f);
                        smem[rl * EPI_STRIDE + cl] = (bf16)v;
                    }
        }
        __syncthreads();
#pragma unroll
        for (int q = 0; q < 4; q++) {
            int flat = q * 256 + t;
            int rl = flat >> 4, seg = flat & 15;
            int grow = row0 + p * 64 + rl;
            if (grow < M)
                *(bf16x8*)&out[(size_t)grow * 256 + col0 + seg * 8] =
                    *(const bf16x8*)&smem[rl * EPI_STRIDE + seg * 8];
        }
        __syncthreads();
    }
}

// Fused W+Wr GEMM: Bt2 is 512x256. cols 0-255 -> out_lo (no act), cols 256-511 ->
// out_hi = relu(.+bias_hi). grid (4, ceil(M/128)).
__global__ __launch_bounds__(256) void mfma_gemm_fused_kernel(
    const bf16* __restrict__ A, const bf16* __restrict__ Bt2,
    const float* __restrict__ bias_hi,
    bf16* __restrict__ out_lo, bf16* __restrict__ out_hi, int M) {
    __shared__ bf16 smem[16384];
    bf16* As = smem;
    bf16* Bs = smem + 8192;

    const int t    = threadIdx.x;
    const int lane = t & 63;
    const int w    = t >> 6;
    const int row0 = blockIdx.y * 128;
    const int col0 = blockIdx.x * 128;   // 0..384

    f32x4 acc[4][4] = {};
    const int wm = (w >> 1) * 64, wn = (w & 1) * 64;
    const int fm = lane & 15, fC = lane >> 4;

    for (int k0 = 0; k0 < 256; k0 += 32) {
#pragma unroll
        for (int r = 0; r < 2; r++) {
            int flat = r * 256 + t;
            int fr = flat >> 2, fc = flat & 3;
            int fcg = fc ^ ((fr >> 1) & 3);
            int arow = row0 + fr;
            if (arow > M - 1) arow = M - 1;
            gl_lds16(&A[(size_t)arow * 256 + k0 + fcg * 8], &As[flat * 8]);
        }
#pragma unroll
        for (int r = 0; r < 2; r++) {
            int flat = r * 256 + t;
            int fr = flat >> 2, fc = flat & 3;
            int fcg = fc ^ ((fr >> 1) & 3);
            int brow = col0 + fr;
            gl_lds16(&Bt2[(size_t)brow * 256 + k0 + fcg * 8], &Bs[flat * 8]);
        }
        __syncthreads();

        bf16x8 af[4], bfr[4];
#pragma unroll
        for (int i = 0; i < 4; i++) af[i] = frag_ld(As, wm + i * 16 + fm, fC);
#pragma unroll
        for (int i = 0; i < 4; i++) bfr[i] = frag_ld(Bs, wn + i * 16 + fm, fC);
#pragma unroll
        for (int i = 0; i < 4; i++)
#pragma unroll
            for (int j = 0; j < 4; j++)
                acc[i][j] = __builtin_amdgcn_mfma_f32_16x16x32_bf16(af[i], bfr[j], acc[i][j], 0, 0, 0);
        __syncthreads();
    }

    const bool hi = (col0 >= 256);          // block-uniform
    bf16* out = hi ? out_hi : out_lo;
    const int cb = hi ? col0 - 256 : col0;

    float bv[4];
#pragma unroll
    for (int j = 0; j < 4; j++) {
        int col = cb + wn + fm + j * 16;
        bv[j] = hi ? bias_hi[col] : 0.f;
    }

#pragma unroll
    for (int p = 0; p < 2; p++) {
        if ((w >> 1) == p) {
#pragma unroll
            for (int i = 0; i < 4; i++)
#pragma unroll
                for (int j = 0; j < 4; j++)
#pragma unroll
                    for (int r2 = 0; r2 < 4; r2++) {
                        int rl = i * 16 + (lane >> 4) * 4 + r2;
                        int cl = wn + fm + j * 16;
                        float v = acc[i][j][r2] + bv[j];
                        if (hi) v = fmaxf(v, 0.f);
                        smem[rl * EPI_STRIDE + cl] = (bf16)v;
                    }
        }
        __syncthreads();
#pragma unroll
        for (int q = 0; q < 4; q++) {
            int flat = q * 256 + t;
            int rl = flat >> 4, seg = flat & 15;
            int grow = row0 + p * 64 + rl;
            if (grow < M)
                *(bf16x8*)&out[(size_t)grow * 256 + cb + seg * 8] =
                    *(const bf16x8*)&smem[rl * EPI_STRIDE + seg * 8];
        }
        __syncthreads();
    }
}

// ---------------------------------------------------------------------------
// edge aggregation + combine (bf16 in/out, fp32 accumulate):
// H[v] = relu(sum_{e: dst=v} hW[src[e]] + b) + res[v]
// one wave per dst node; lane covers 8 feats (16B), half-waves cover 2 edges.
// ---------------------------------------------------------------------------
__global__ __launch_bounds__(256) void agg_combine_kernel(const bf16* __restrict__ hW,
                                                          const int* __restrict__ csr_src,
                                                          const int* __restrict__ offsets,
                                                          const float* __restrict__ bias,
                                                          const bf16* __restrict__ res,
                                                          bf16* __restrict__ H, int n_nodes) {
    int wave = threadIdx.x >> 6;
    int lane = threadIdx.x & 63;
    int node = blockIdx.x * 4 + wave;
    if (node >= n_nodes) return;
    int beg = offsets[node], end = offsets[node + 1];
    const int half = lane >> 5;
    const int fo   = (lane & 31) * 8;

    float acc[8] = {};
    int j = beg;
    for (; j + 2 + half < end; j += 4) {
        int s0 = csr_src[j + half];
        int s1 = csr_src[j + 2 + half];
        bf16x8 v0 = *(const bf16x8*)&hW[(size_t)s0 * DD + fo];
        bf16x8 v1 = *(const bf16x8*)&hW[(size_t)s1 * DD + fo];
#pragma unroll
        for (int q = 0; q < 8; q++) acc[q] += (float)v0[q];
#pragma unroll
        for (int q = 0; q < 8; q++) acc[q] += (float)v1[q];
    }
    for (; j + half < end; j += 2) {
        int s = csr_src[j + half];
        bf16x8 v = *(const bf16x8*)&hW[(size_t)s * DD + fo];
#pragma unroll
        for (int q = 0; q < 8; q++) acc[q] += (float)v[q];
    }
#pragma unroll
    for (int q = 0; q < 8; q++) acc[q] += __shfl_xor(acc[q], 32, 64);

    if (half == 0) {
        float4 b0 = *(const float4*)&bias[fo];
        float4 b1 = *(const float4*)&bias[fo + 4];
        bf16x8 rv = *(const bf16x8*)&res[(size_t)node * DD + fo];
        bf16x8 o;
        o[0] = (bf16)(fmaxf(acc[0] + b0.x, 0.f) + (float)rv[0]);
        o[1] = (bf16)(fmaxf(acc[1] + b0.y, 0.f) + (float)rv[1]);
        o[2] = (bf16)(fmaxf(acc[2] + b0.z, 0.f) + (float)rv[2]);
        o[3] = (bf16)(fmaxf(acc[3] + b0.w, 0.f) + (float)rv[3]);
        o[4] = (bf16)(fmaxf(acc[4] + b1.x, 0.f) + (float)rv[4]);
        o[5] = (bf16)(fmaxf(acc[5] + b1.y, 0.f) + (float)rv[5]);
        o[6] = (bf16)(fmaxf(acc[6] + b1.z, 0.f) + (float)rv[6]);
        o[7] = (bf16)(fmaxf(acc[7] + b1.w, 0.f) + (float)rv[7]);
        *(bf16x8*)&H[(size_t)node * DD + fo] = o;
    }
}

// ---------------------------------------------------------------------------
// per-graph segment sum of P[N_nodes, 256(stride)] bf16, cols<GFEAT; block per graph
// ---------------------------------------------------------------------------
__global__ __launch_bounds__(256) void graph_reduce_kernel(const bf16* __restrict__ P,
                                                           const int* __restrict__ gids,
                                                           float* __restrict__ G, int n_nodes) {
    int g = blockIdx.x;
    int lo = 0, hi = n_nodes;
    while (lo < hi) { int mid = (lo + hi) >> 1; if (gids[mid] < g) lo = mid + 1; else hi = mid; }
    int beg = lo;
    hi = n_nodes;
    while (lo < hi) { int mid = (lo + hi) >> 1; if (gids[mid] < g + 1) lo = mid + 1; else hi = mid; }
    int end = lo;

    int c = threadIdx.x;
    if (c < GFEAT) {
        float acc = 0.f;
        for (int r = beg; r < end; r++) acc += (float)P[(size_t)r * 256 + c];
        G[(size_t)g * GFEAT + c] = acc;
    }
}

__global__ __launch_bounds__(256) void predictor_kernel(const float* __restrict__ G1,
                                                        const float* __restrict__ G2,
                                                        const float* __restrict__ Wp,
                                                        const float* __restrict__ bp,
                                                        float* __restrict__ out) {
    int i = blockIdx.x * 256 + threadIdx.x;
    if (i >= NG) return;
    float acc = bp[0];
    for (int f = 0; f < GFEAT; f++)
        acc += (G1[i * GFEAT + f] + G2[i * GFEAT + f]) * Wp[f];
    out[i] = acc;
}

// ---------------------------------------------------------------------------
// host-side branch driver (CSR already built)
// ---------------------------------------------------------------------------
static void run_branch(const bf16* Xb, const int* gids,
                       const bf16* WWr, const float* b, const float* br,
                       const bf16* Rit, const float* rbi, const bf16* Rot, const float* rbo,
                       float* Gout, bf16* hWb, bf16* resb, bf16* Hb, bf16* P,
                       const int* offs, const int* csr, hipStream_t stream) {
    dim3 gf(4, (NN + 127) / 128);
    dim3 g2(2, (NN + 127) / 128);
    // hW = X @ W ; res = relu(X @ Wr + br)
    mfma_gemm_fused_kernel<<<gf, 256, 0, stream>>>(Xb, WWr, br, hWb, resb, NN);
    // H = relu(agg + b) + res
    agg_combine_kernel<<<(NN + 3) / 4, 256, 0, stream>>>(hWb, csr, offs, b, resb, Hb, NN);
    // R = relu(H @ Ri + rbi) -> reuse hWb
    mfma_gemm_kernel<<<g2, 256, 0, stream>>>(Hb, Rit, rbi, hWb, NN, DD, DD, 1);
    // P = R @ Ro + rbo (bf16, stride 256, cols<200 valid)
    mfma_gemm_kernel<<<g2, 256, 0, stream>>>(hWb, Rot, rbo, P, NN, DD, GFEAT, 0);
    // G = segment_sum(P, gids)
    graph_reduce_kernel<<<NG, 256, 0, stream>>>(P, gids, Gout, NN);
}

extern "C" void kernel_launch(void* const* d_in, const int* in_sizes, int n_in,
                              void* d_out, int out_size, void* d_ws, size_t ws_size,
                              hipStream_t stream) {
    const float* X1   = (const float*)d_in[0];
    const float* X2   = (const float*)d_in[2];
    const int*   src1 = (const int*)d_in[4];
    const int*   dst1 = (const int*)d_in[5];
    const int*   gid1 = (const int*)d_in[6];
    const int*   src2 = (const int*)d_in[7];
    const int*   dst2 = (const int*)d_in[8];
    const int*   gid2 = (const int*)d_in[9];
    const float* W1  = (const float*)d_in[10]; const float* b1  = (const float*)d_in[11];
    const float* Wr1 = (const float*)d_in[12]; const float* br1 = (const float*)d_in[13];
    const float* W2  = (const float*)d_in[14]; const float* b2  = (const float*)d_in[15];
    const float* Wr2 = (const float*)d_in[16]; const float* br2 = (const float*)d_in[17];
    const float* Ri1 = (const float*)d_in[18]; const float* rbi1 = (const float*)d_in[19];
    const float* Ro1 = (const float*)d_in[20]; const float* rbo1 = (const float*)d_in[21];
    const float* Ri2 = (const float*)d_in[22]; const float* rbi2 = (const float*)d_in[23];
    const float* Ro2 = (const float*)d_in[24]; const float* rbo2 = (const float*)d_in[25];
    const float* Wp  = (const float*)d_in[26]; const float* bp  = (const float*)d_in[27];

    // workspace layout
    char* p = (char*)d_ws;
    bf16* Xb1  = (bf16*)p; p += (size_t)NN * DD * sizeof(bf16);
    bf16* Xb2  = (bf16*)p; p += (size_t)NN * DD * sizeof(bf16);
    bf16* hWb  = (bf16*)p; p += (size_t)NN * DD * sizeof(bf16);
    bf16* resb = (bf16*)p; p += (size_t)NN * DD * sizeof(bf16);
    bf16* Hb   = (bf16*)p; p += (size_t)NN * DD * sizeof(bf16);
    bf16* P    = (bf16*)p; p += (size_t)NN * 256 * sizeof(bf16);
    float* G1  = (float*)p; p += (size_t)NG * GFEAT * sizeof(float);
    float* G2  = (float*)p; p += (size_t)NG * GFEAT * sizeof(float);
    // 8 weight mats; order: W1,Wr1,Ri1,Ro1,W2,Wr2,Ri2,Ro2 (W|Wr contiguous = fused Bt)
    bf16* Wbase = (bf16*)p; p += 8 * 65536 * sizeof(bf16);
    int* offs1 = (int*)p; p += (NN + 1) * sizeof(int);
    int* offs2 = (int*)p; p += (NN + 1) * sizeof(int);
    int* btot1 = (int*)p; p += NB_B * sizeof(int);
    int* btot2 = (int*)p; p += NB_B * sizeof(int);
    int* csr1  = (int*)p; p += NE * sizeof(int);
    int* csr2  = (int*)p;

    conv_w8_kernel<<<dim3(256, 8), 256, 0, stream>>>(W1, Wr1, Ri1, Ro1, W2, Wr2, Ri2, Ro2, Wbase);
    conv_x2_kernel<<<dim3((NN * DD / 4 + 255) / 256, 2), 256, 0, stream>>>(
        X1, X2, Xb1, Xb2, NN * DD / 4);

    // CSR build (both branches), no global atomics
    csr_hist_kernel<<<dim3(NB_B, 2), 512, 0, stream>>>(dst1, dst2, offs1, offs2, btot1, btot2);
    csr_bases_kernel<<<dim3(1, 2), 128, 0, stream>>>(btot1, btot2, offs1, offs2);
    csr_scatter_kernel<<<dim3(NB_B, 2), 512, 0, stream>>>(
        src1, src2, dst1, dst2, offs1, offs2, btot1, btot2, csr1, csr2);

    run_branch(Xb1, gid1, Wbase + 0 * 65536, b1, br1,
               Wbase + 2 * 65536, rbi1, Wbase + 3 * 65536, rbo1,
               G1, hWb, resb, Hb, P, offs1, csr1, stream);
    run_branch(Xb2, gid2, Wbase + 4 * 65536, b2, br2,
               Wbase + 6 * 65536, rbi2, Wbase + 7 * 65536, rbo2,
               G2, hWb, resb, Hb, P, offs2, csr2, stream);

    predictor_kernel<<<(NG + 255) / 256, 256, 0, stream>>>(G1, G2, Wp, bp, (float*)d_out);
}

// Round 2
// 653.520 us; speedup vs baseline: 1.6052x; 1.6052x over previous
//
#include <hip/hip_runtime.h>

// Problem constants (fixed by reference)
#define NN 50000      // nodes
#define NE 800000     // edges
#define DD 256        // node feat dim
#define GFEAT 200     // graph feat dim
#define NG 512        // graphs

typedef __bf16 bf16;
typedef bf16 bf16x4 __attribute__((ext_vector_type(4)));
typedef bf16 bf16x8 __attribute__((ext_vector_type(8)));
typedef float f32x4 __attribute__((ext_vector_type(4)));

// async global->LDS, 16B per lane. HW dest = wave-uniform base + lane*16.
__device__ __forceinline__ void gl_lds16(const bf16* g, bf16* l) {
    __builtin_amdgcn_global_load_lds(
        (const __attribute__((address_space(1))) uint32_t*)(g),
        (__attribute__((address_space(3))) uint32_t*)(l), 16, 0, 0);
}

// swizzled fragment read: LDS [row][32k] where chunk c holds global chunk c^((row>>1)&3)
__device__ __forceinline__ bf16x8 frag_ld(const bf16* s, int R, int C) {
    return *(const bf16x8*)&s[R * 32 + ((C ^ ((R >> 1) & 3)) << 3)];
}

#define EPI_STRIDE 136   // bf16 elems; 272 B row stride (16B-aligned, bank-shift 4/row)

// ---------------------------------------------------------------------------
// conversions
// ---------------------------------------------------------------------------
__global__ __launch_bounds__(256) void conv_x2_kernel(const float* __restrict__ in0,
                                                      const float* __restrict__ in1,
                                                      bf16* __restrict__ out0,
                                                      bf16* __restrict__ out1, int n4) {
    const float* in = blockIdx.y ? in1 : in0;
    bf16* out = blockIdx.y ? out1 : out0;
    int i = blockIdx.x * 256 + threadIdx.x;
    if (i < n4) {
        float4 v = ((const float4*)in)[i];
        bf16x4 o;
        o[0] = (bf16)v.x; o[1] = (bf16)v.y; o[2] = (bf16)v.z; o[3] = (bf16)v.w;
        ((bf16x4*)out)[i] = o;
    }
}

// 8 weight matrices fp32 [K][N] -> bf16 [256][256] = [n][k] transposed, zero-padded.
__global__ __launch_bounds__(256) void conv_w8_kernel(
    const float* __restrict__ w0, const float* __restrict__ w1,
    const float* __restrict__ w2, const float* __restrict__ w3,
    const float* __restrict__ w4, const float* __restrict__ w5,
    const float* __restrict__ w6, const float* __restrict__ w7,
    bf16* __restrict__ out_base) {
    const float* ws[8] = {w0, w1, w2, w3, w4, w5, w6, w7};
    const int Ns[8] = {DD, DD, DD, GFEAT, DD, DD, DD, GFEAT};
    int m = blockIdx.y;
    const float* in = ws[m];
    int N = Ns[m];
    int idx = blockIdx.x * 256 + threadIdx.x;   // 0..65535 over [n][k]
    int n = idx >> 8, k = idx & 255;
    float v = (n < N) ? in[k * N + n] : 0.f;
    out_base[(size_t)m * 65536 + idx] = (bf16)v;
}

// ---------------------------------------------------------------------------
// CSR build: two-level counting sort, zero global atomics, O(1) reads/edge.
//   A: per-chunk coarse hist (128 buckets of 391 nodes) -> cnt[bucket][chunk]
//   B: scan cnt (bucket-major) in place -> start offsets; cnt[b*NCHUNK]=bucket base
//   C: per-chunk partition via LDS cursors (disjoint ranges, no races) -> (src,dst)
//   D: per-bucket LDS counting sort -> offs[] + csr[] (contiguous region writes)
// ---------------------------------------------------------------------------
#define NBKT   128
#define NPB    391            // ceil(NN / NBKT); 128*391 = 50048
#define NCHUNK 256
#define CE     ((NE + NCHUNK - 1) / NCHUNK)   // 3125 edges per chunk

__global__ __launch_bounds__(256) void csr_coarse_hist_kernel(
    const int* __restrict__ d0, const int* __restrict__ d1,
    int* __restrict__ cnt0, int* __restrict__ cnt1) {
    const int blk = blockIdx.x, t = threadIdx.x;
    const int* dst = blockIdx.y ? d1 : d0;
    int* cnt = blockIdx.y ? cnt1 : cnt0;
    __shared__ int hist[NBKT];
    if (t < NBKT) hist[t] = 0;
    __syncthreads();
    const int e0 = blk * CE;
    const int e1 = (e0 + CE < NE) ? e0 + CE : NE;
    for (int e = e0 + t; e < e1; e += 256)
        atomicAdd(&hist[dst[e] / NPB], 1);
    __syncthreads();
    if (t < NBKT) cnt[t * NCHUNK + blk] = hist[t];   // bucket-major
}

__global__ __launch_bounds__(1024) void csr_scan_kernel(
    int* __restrict__ cnt0, int* __restrict__ cnt1,
    int* __restrict__ offs0, int* __restrict__ offs1) {
    int* cnt = blockIdx.y ? cnt1 : cnt0;
    const int t = threadIdx.x;
    const int PER = (NBKT * NCHUNK) / 1024;   // 32
    int v[PER];
    int sum = 0;
    const int base = t * PER;
#pragma unroll
    for (int i = 0; i < PER; i += 4) {
        int4 q = *(const int4*)&cnt[base + i];
        v[i] = q.x; v[i + 1] = q.y; v[i + 2] = q.z; v[i + 3] = q.w;
        sum += q.x + q.y + q.z + q.w;
    }
    __shared__ int s[1024];
    s[t] = sum;
    __syncthreads();
    for (int off = 1; off < 1024; off <<= 1) {
        int a = (t >= off) ? s[t - off] : 0;
        __syncthreads();
        s[t] += a;
        __syncthreads();
    }
    int run = s[t] - sum;   // exclusive prefix of this thread's chunk
#pragma unroll
    for (int i = 0; i < PER; i++) { int c = v[i]; cnt[base + i] = run; run += c; }
    if (t == 0) (blockIdx.y ? offs1 : offs0)[NN] = NE;
}

__global__ __launch_bounds__(256) void csr_partition_kernel(
    const int* __restrict__ sA, const int* __restrict__ sB,
    const int* __restrict__ d0, const int* __restrict__ d1,
    const int* __restrict__ cnt0, const int* __restrict__ cnt1,
    int2* __restrict__ eb0, int2* __restrict__ eb1) {
    const int blk = blockIdx.x, t = threadIdx.x;
    const int* src = blockIdx.y ? sB : sA;
    const int* dst = blockIdx.y ? d1 : d0;
    const int* cnt = blockIdx.y ? cnt1 : cnt0;
    int2* eb = blockIdx.y ? eb1 : eb0;
    __shared__ int cur[NBKT];
    if (t < NBKT) cur[t] = cnt[t * NCHUNK + blk];   // this chunk's start in each bucket
    __syncthreads();
    const int e0 = blk * CE;
    const int e1 = (e0 + CE < NE) ? e0 + CE : NE;
    for (int e = e0 + t; e < e1; e += 256) {
        int d = dst[e], s = src[e];
        int pos = atomicAdd(&cur[d / NPB], 1);      // LDS atomic, range disjoint per block
        eb[pos] = make_int2(s, d);
    }
}

__global__ __launch_bounds__(512) void csr_bucket_sort_kernel(
    const int* __restrict__ cnt0, const int* __restrict__ cnt1,
    const int2* __restrict__ eb0, const int2* __restrict__ eb1,
    int* __restrict__ offs0, int* __restrict__ offs1,
    int* __restrict__ csr0, int* __restrict__ csr1) {
    const int b = blockIdx.x, t = threadIdx.x;
    const int* cnt = blockIdx.y ? cnt1 : cnt0;
    const int2* eb = blockIdx.y ? eb1 : eb0;
    int* offs = blockIdx.y ? offs1 : offs0;
    int* csr = blockIdx.y ? csr1 : csr0;
    const int lo = b * NPB;
    const int ncnt = (NN - lo < NPB) ? (NN - lo) : NPB;
    const int beg = cnt[b * NCHUNK];
    const int end = (b == NBKT - 1) ? NE : cnt[(b + 1) * NCHUNK];

    __shared__ int hist[NPB];
    __shared__ int s[512];
    if (t < NPB) hist[t] = 0;
    __syncthreads();
    for (int i = beg + t; i < end; i += 512)
        atomicAdd(&hist[eb[i].y - lo], 1);
    __syncthreads();

    int h = (t < NPB) ? hist[t] : 0;
    s[t] = h;
    __syncthreads();
    for (int off = 1; off < 512; off <<= 1) {
        int a = (t >= off) ? s[t - off] : 0;
        __syncthreads();
        s[t] += a;
        __syncthreads();
    }
    int excl = s[t] - h;
    __syncthreads();
    if (t < NPB) hist[t] = excl;                 // local cursors
    if (t < ncnt) offs[lo + t] = beg + excl;     // final global offsets
    __syncthreads();

    for (int i = beg + t; i < end; i += 512) {
        int2 v = eb[i];
        int pos = atomicAdd(&hist[v.y - lo], 1);
        csr[beg + pos] = v.x;                    // contiguous ~25 KB region per block
    }
}

// ---------------------------------------------------------------------------
// bf16 MFMA GEMM (generic, bf16 out, storage width outW=256):
// C[M,0..N) = A[M,K] @ Bt[N,K]^T (+bias on cols<Nb) (+relu)
// 128x128 tile, BK=32, 256 threads (4 waves 2x2), swizzled LDS, LDS epilogue.
// ---------------------------------------------------------------------------
__global__ __launch_bounds__(256) void mfma_gemm_kernel(
    const bf16* __restrict__ A, const bf16* __restrict__ Bt,
    const float* __restrict__ bias, bf16* __restrict__ out,
    int M, int K, int Nb, int do_relu) {
    __shared__ bf16 smem[16384];     // As | Bs during K-loop; epilogue buffer after
    bf16* As = smem;
    bf16* Bs = smem + 8192;

    const int t    = threadIdx.x;
    const int lane = t & 63;
    const int w    = t >> 6;
    const int row0 = blockIdx.y * 128;
    const int col0 = blockIdx.x * 128;

    f32x4 acc[4][4] = {};
    const int wm = (w >> 1) * 64, wn = (w & 1) * 64;
    const int fm = lane & 15, fC = lane >> 4;

    for (int k0 = 0; k0 < K; k0 += 32) {
#pragma unroll
        for (int r = 0; r < 2; r++) {
            int flat = r * 256 + t;
            int fr = flat >> 2, fc = flat & 3;
            int fcg = fc ^ ((fr >> 1) & 3);          // swizzle
            int arow = row0 + fr;
            if (arow > M - 1) arow = M - 1;
            gl_lds16(&A[(size_t)arow * K + k0 + fcg * 8], &As[flat * 8]);
        }
#pragma unroll
        for (int r = 0; r < 2; r++) {
            int flat = r * 256 + t;
            int fr = flat >> 2, fc = flat & 3;
            int fcg = fc ^ ((fr >> 1) & 3);
            int brow = col0 + fr;                    // Bt padded
            gl_lds16(&Bt[(size_t)brow * K + k0 + fcg * 8], &Bs[flat * 8]);
        }
        __syncthreads();

        bf16x8 af[4], bfr[4];
#pragma unroll
        for (int i = 0; i < 4; i++) af[i] = frag_ld(As, wm + i * 16 + fm, fC);
#pragma unroll
        for (int i = 0; i < 4; i++) bfr[i] = frag_ld(Bs, wn + i * 16 + fm, fC);
#pragma unroll
        for (int i = 0; i < 4; i++)
#pragma unroll
            for (int j = 0; j < 4; j++)
                acc[i][j] = __builtin_amdgcn_mfma_f32_16x16x32_bf16(af[i], bfr[j], acc[i][j], 0, 0, 0);
        __syncthreads();
    }

    // bias per j (cols wn+fm+j*16)
    float bv[4];
#pragma unroll
    for (int j = 0; j < 4; j++) {
        int col = col0 + wn + fm + j * 16;
        bv[j] = (bias && col < Nb) ? bias[col] : 0.f;
    }

    // epilogue: 2 passes of 64 rows through LDS, then 16B coalesced stores
#pragma unroll
    for (int p = 0; p < 2; p++) {
        if ((w >> 1) == p) {
#pragma unroll
            for (int i = 0; i < 4; i++)
#pragma unroll
                for (int j = 0; j < 4; j++)
#pragma unroll
                    for (int r2 = 0; r2 < 4; r2++) {
                        int rl = i * 16 + (lane >> 4) * 4 + r2;   // 0..63
                        int cl = wn + fm + j * 16;                // 0..127
                        float v = acc[i][j][r2] + bv[j];
                        if (do_relu) v = fmaxf(v, 0.f);
                        smem[rl * EPI_STRIDE + cl] = (bf16)v;
                    }
        }
        __syncthreads();
#pragma unroll
        for (int q = 0; q < 4; q++) {
            int flat = q * 256 + t;
            int rl = flat >> 4, seg = flat & 15;
            int grow = row0 + p * 64 + rl;
            if (grow < M)
                *(bf16x8*)&out[(size_t)grow * 256 + col0 + seg * 8] =
                    *(const bf16x8*)&smem[rl * EPI_STRIDE + seg * 8];
        }
        __syncthreads();
    }
}

// Fused W+Wr GEMM: Bt2 is 512x256. cols 0-255 -> out_lo (no act), cols 256-511 ->
// out_hi = relu(.+bias_hi). grid (4, ceil(M/128)).
__global__ __launch_bounds__(256) void mfma_gemm_fused_kernel(
    const bf16* __restrict__ A, const bf16* __restrict__ Bt2,
    const float* __restrict__ bias_hi,
    bf16* __restrict__ out_lo, bf16* __restrict__ out_hi, int M) {
    __shared__ bf16 smem[16384];
    bf16* As = smem;
    bf16* Bs = smem + 8192;

    const int t    = threadIdx.x;
    const int lane = t & 63;
    const int w    = t >> 6;
    const int row0 = blockIdx.y * 128;
    const int col0 = blockIdx.x * 128;   // 0..384

    f32x4 acc[4][4] = {};
    const int wm = (w >> 1) * 64, wn = (w & 1) * 64;
    const int fm = lane & 15, fC = lane >> 4;

    for (int k0 = 0; k0 < 256; k0 += 32) {
#pragma unroll
        for (int r = 0; r < 2; r++) {
            int flat = r * 256 + t;
            int fr = flat >> 2, fc = flat & 3;
            int fcg = fc ^ ((fr >> 1) & 3);
            int arow = row0 + fr;
            if (arow > M - 1) arow = M - 1;
            gl_lds16(&A[(size_t)arow * 256 + k0 + fcg * 8], &As[flat * 8]);
        }
#pragma unroll
        for (int r = 0; r < 2; r++) {
            int flat = r * 256 + t;
            int fr = flat >> 2, fc = flat & 3;
            int fcg = fc ^ ((fr >> 1) & 3);
            int brow = col0 + fr;
            gl_lds16(&Bt2[(size_t)brow * 256 + k0 + fcg * 8], &Bs[flat * 8]);
        }
        __syncthreads();

        bf16x8 af[4], bfr[4];
#pragma unroll
        for (int i = 0; i < 4; i++) af[i] = frag_ld(As, wm + i * 16 + fm, fC);
#pragma unroll
        for (int i = 0; i < 4; i++) bfr[i] = frag_ld(Bs, wn + i * 16 + fm, fC);
#pragma unroll
        for (int i = 0; i < 4; i++)
#pragma unroll
            for (int j = 0; j < 4; j++)
                acc[i][j] = __builtin_amdgcn_mfma_f32_16x16x32_bf16(af[i], bfr[j], acc[i][j], 0, 0, 0);
        __syncthreads();
    }

    const bool hi = (col0 >= 256);          // block-uniform
    bf16* out = hi ? out_hi : out_lo;
    const int cb = hi ? col0 - 256 : col0;

    float bv[4];
#pragma unroll
    for (int j = 0; j < 4; j++) {
        int col = cb + wn + fm + j * 16;
        bv[j] = hi ? bias_hi[col] : 0.f;
    }

#pragma unroll
    for (int p = 0; p < 2; p++) {
        if ((w >> 1) == p) {
#pragma unroll
            for (int i = 0; i < 4; i++)
#pragma unroll
                for (int j = 0; j < 4; j++)
#pragma unroll
                    for (int r2 = 0; r2 < 4; r2++) {
                        int rl = i * 16 + (lane >> 4) * 4 + r2;
                        int cl = wn + fm + j * 16;
                        float v = acc[i][j][r2] + bv[j];
                        if (hi) v = fmaxf(v, 0.f);
                        smem[rl * EPI_STRIDE + cl] = (bf16)v;
                    }
        }
        __syncthreads();
#pragma unroll
        for (int q = 0; q < 4; q++) {
            int flat = q * 256 + t;
            int rl = flat >> 4, seg = flat & 15;
            int grow = row0 + p * 64 + rl;
            if (grow < M)
                *(bf16x8*)&out[(size_t)grow * 256 + cb + seg * 8] =
                    *(const bf16x8*)&smem[rl * EPI_STRIDE + seg * 8];
        }
        __syncthreads();
    }
}

// ---------------------------------------------------------------------------
// edge aggregation + combine (bf16 in/out, fp32 accumulate):
// H[v] = relu(sum_{e: dst=v} hW[src[e]] + b) + res[v]
// one wave per dst node; lane covers 8 feats (16B), half-waves cover 2 edges.
// ---------------------------------------------------------------------------
__global__ __launch_bounds__(256) void agg_combine_kernel(const bf16* __restrict__ hW,
                                                          const int* __restrict__ csr_src,
                                                          const int* __restrict__ offsets,
                                                          const float* __restrict__ bias,
                                                          const bf16* __restrict__ res,
                                                          bf16* __restrict__ H, int n_nodes) {
    int wave = threadIdx.x >> 6;
    int lane = threadIdx.x & 63;
    int node = blockIdx.x * 4 + wave;
    if (node >= n_nodes) return;
    int beg = offsets[node], end = offsets[node + 1];
    const int half = lane >> 5;
    const int fo   = (lane & 31) * 8;

    float acc[8] = {};
    int j = beg;
    for (; j + 2 + half < end; j += 4) {
        int s0 = csr_src[j + half];
        int s1 = csr_src[j + 2 + half];
        bf16x8 v0 = *(const bf16x8*)&hW[(size_t)s0 * DD + fo];
        bf16x8 v1 = *(const bf16x8*)&hW[(size_t)s1 * DD + fo];
#pragma unroll
        for (int q = 0; q < 8; q++) acc[q] += (float)v0[q];
#pragma unroll
        for (int q = 0; q < 8; q++) acc[q] += (float)v1[q];
    }
    for (; j + half < end; j += 2) {
        int s = csr_src[j + half];
        bf16x8 v = *(const bf16x8*)&hW[(size_t)s * DD + fo];
#pragma unroll
        for (int q = 0; q < 8; q++) acc[q] += (float)v[q];
    }
#pragma unroll
    for (int q = 0; q < 8; q++) acc[q] += __shfl_xor(acc[q], 32, 64);

    if (half == 0) {
        float4 b0 = *(const float4*)&bias[fo];
        float4 b1 = *(const float4*)&bias[fo + 4];
        bf16x8 rv = *(const bf16x8*)&res[(size_t)node * DD + fo];
        bf16x8 o;
        o[0] = (bf16)(fmaxf(acc[0] + b0.x, 0.f) + (float)rv[0]);
        o[1] = (bf16)(fmaxf(acc[1] + b0.y, 0.f) + (float)rv[1]);
        o[2] = (bf16)(fmaxf(acc[2] + b0.z, 0.f) + (float)rv[2]);
        o[3] = (bf16)(fmaxf(acc[3] + b0.w, 0.f) + (float)rv[3]);
        o[4] = (bf16)(fmaxf(acc[4] + b1.x, 0.f) + (float)rv[4]);
        o[5] = (bf16)(fmaxf(acc[5] + b1.y, 0.f) + (float)rv[5]);
        o[6] = (bf16)(fmaxf(acc[6] + b1.z, 0.f) + (float)rv[6]);
        o[7] = (bf16)(fmaxf(acc[7] + b1.w, 0.f) + (float)rv[7]);
        *(bf16x8*)&H[(size_t)node * DD + fo] = o;
    }
}

// ---------------------------------------------------------------------------
// per-graph segment sum of P[N_nodes, 256(stride)] bf16, cols<GFEAT; block per graph
// ---------------------------------------------------------------------------
__global__ __launch_bounds__(256) void graph_reduce_kernel(const bf16* __restrict__ P,
                                                           const int* __restrict__ gids,
                                                           float* __restrict__ G, int n_nodes) {
    int g = blockIdx.x;
    int lo = 0, hi = n_nodes;
    while (lo < hi) { int mid = (lo + hi) >> 1; if (gids[mid] < g) lo = mid + 1; else hi = mid; }
    int beg = lo;
    hi = n_nodes;
    while (lo < hi) { int mid = (lo + hi) >> 1; if (gids[mid] < g + 1) lo = mid + 1; else hi = mid; }
    int end = lo;

    int c = threadIdx.x;
    if (c < GFEAT) {
        float acc = 0.f;
        for (int r = beg; r < end; r++) acc += (float)P[(size_t)r * 256 + c];
        G[(size_t)g * GFEAT + c] = acc;
    }
}

__global__ __launch_bounds__(256) void predictor_kernel(const float* __restrict__ G1,
                                                        const float* __restrict__ G2,
                                                        const float* __restrict__ Wp,
                                                        const float* __restrict__ bp,
                                                        float* __restrict__ out) {
    int i = blockIdx.x * 256 + threadIdx.x;
    if (i >= NG) return;
    float acc = bp[0];
    for (int f = 0; f < GFEAT; f++)
        acc += (G1[i * GFEAT + f] + G2[i * GFEAT + f]) * Wp[f];
    out[i] = acc;
}

// ---------------------------------------------------------------------------
// host-side branch driver (CSR already built)
// ---------------------------------------------------------------------------
static void run_branch(const bf16* Xb, const int* gids,
                       const bf16* WWr, const float* b, const float* br,
                       const bf16* Rit, const float* rbi, const bf16* Rot, const float* rbo,
                       float* Gout, bf16* hWb, bf16* resb, bf16* Hb, bf16* P,
                       const int* offs, const int* csr, hipStream_t stream) {
    dim3 gf(4, (NN + 127) / 128);
    dim3 g2(2, (NN + 127) / 128);
    // hW = X @ W ; res = relu(X @ Wr + br)
    mfma_gemm_fused_kernel<<<gf, 256, 0, stream>>>(Xb, WWr, br, hWb, resb, NN);
    // H = relu(agg + b) + res
    agg_combine_kernel<<<(NN + 3) / 4, 256, 0, stream>>>(hWb, csr, offs, b, resb, Hb, NN);
    // R = relu(H @ Ri + rbi) -> reuse hWb
    mfma_gemm_kernel<<<g2, 256, 0, stream>>>(Hb, Rit, rbi, hWb, NN, DD, DD, 1);
    // P = R @ Ro + rbo (bf16, stride 256, cols<200 valid)
    mfma_gemm_kernel<<<g2, 256, 0, stream>>>(hWb, Rot, rbo, P, NN, DD, GFEAT, 0);
    // G = segment_sum(P, gids)
    graph_reduce_kernel<<<NG, 256, 0, stream>>>(P, gids, Gout, NN);
}

extern "C" void kernel_launch(void* const* d_in, const int* in_sizes, int n_in,
                              void* d_out, int out_size, void* d_ws, size_t ws_size,
                              hipStream_t stream) {
    const float* X1   = (const float*)d_in[0];
    const float* X2   = (const float*)d_in[2];
    const int*   src1 = (const int*)d_in[4];
    const int*   dst1 = (const int*)d_in[5];
    const int*   gid1 = (const int*)d_in[6];
    const int*   src2 = (const int*)d_in[7];
    const int*   dst2 = (const int*)d_in[8];
    const int*   gid2 = (const int*)d_in[9];
    const float* W1  = (const float*)d_in[10]; const float* b1  = (const float*)d_in[11];
    const float* Wr1 = (const float*)d_in[12]; const float* br1 = (const float*)d_in[13];
    const float* W2  = (const float*)d_in[14]; const float* b2  = (const float*)d_in[15];
    const float* Wr2 = (const float*)d_in[16]; const float* br2 = (const float*)d_in[17];
    const float* Ri1 = (const float*)d_in[18]; const float* rbi1 = (const float*)d_in[19];
    const float* Ro1 = (const float*)d_in[20]; const float* rbo1 = (const float*)d_in[21];
    const float* Ri2 = (const float*)d_in[22]; const float* rbi2 = (const float*)d_in[23];
    const float* Ro2 = (const float*)d_in[24]; const float* rbo2 = (const float*)d_in[25];
    const float* Wp  = (const float*)d_in[26]; const float* bp  = (const float*)d_in[27];

    // workspace layout
    char* p = (char*)d_ws;
    bf16* Xb1  = (bf16*)p; p += (size_t)NN * DD * sizeof(bf16);
    bf16* Xb2  = (bf16*)p; p += (size_t)NN * DD * sizeof(bf16);
    bf16* hWb  = (bf16*)p; p += (size_t)NN * DD * sizeof(bf16);
    bf16* resb = (bf16*)p; p += (size_t)NN * DD * sizeof(bf16);
    bf16* Hb   = (bf16*)p; p += (size_t)NN * DD * sizeof(bf16);
    bf16* P    = (bf16*)p; p += (size_t)NN * 256 * sizeof(bf16);
    float* G1  = (float*)p; p += (size_t)NG * GFEAT * sizeof(float);
    float* G2  = (float*)p; p += (size_t)NG * GFEAT * sizeof(float);
    // 8 weight mats; order: W1,Wr1,Ri1,Ro1,W2,Wr2,Ri2,Ro2 (W|Wr contiguous = fused Bt)
    bf16* Wbase = (bf16*)p; p += 8 * 65536 * sizeof(bf16);
    int* offs1 = (int*)p; p += (NN + 1) * sizeof(int);
    int* offs2 = (int*)p; p += (NN + 1) * sizeof(int);
    int* cnt1  = (int*)p; p += NBKT * NCHUNK * sizeof(int);
    int* cnt2  = (int*)p; p += NBKT * NCHUNK * sizeof(int);
    int* csr1  = (int*)p; p += NE * sizeof(int);
    int* csr2  = (int*)p; p += NE * sizeof(int);
    // edge-pair buffers alias P: only live during CSR build, P written later.
    int2* eb1 = (int2*)P;
    int2* eb2 = (int2*)P + NE;

    conv_w8_kernel<<<dim3(256, 8), 256, 0, stream>>>(W1, Wr1, Ri1, Ro1, W2, Wr2, Ri2, Ro2, Wbase);
    conv_x2_kernel<<<dim3((NN * DD / 4 + 255) / 256, 2), 256, 0, stream>>>(
        X1, X2, Xb1, Xb2, NN * DD / 4);

    // CSR build (both branches): two-level counting sort, no global atomics
    csr_coarse_hist_kernel<<<dim3(NCHUNK, 2), 256, 0, stream>>>(dst1, dst2, cnt1, cnt2);
    csr_scan_kernel<<<dim3(1, 2), 1024, 0, stream>>>(cnt1, cnt2, offs1, offs2);
    csr_partition_kernel<<<dim3(NCHUNK, 2), 256, 0, stream>>>(
        src1, src2, dst1, dst2, cnt1, cnt2, eb1, eb2);
    csr_bucket_sort_kernel<<<dim3(NBKT, 2), 512, 0, stream>>>(
        cnt1, cnt2, eb1, eb2, offs1, offs2, csr1, csr2);

    run_branch(Xb1, gid1, Wbase + 0 * 65536, b1, br1,
               Wbase + 2 * 65536, rbi1, Wbase + 3 * 65536, rbo1,
               G1, hWb, resb, Hb, P, offs1, csr1, stream);
    run_branch(Xb2, gid2, Wbase + 4 * 65536, b2, br2,
               Wbase + 6 * 65536, rbi2, Wbase + 7 * 65536, rbo2,
               G2, hWb, resb, Hb, P, offs2, csr2, stream);

    predictor_kernel<<<(NG + 255) / 256, 256, 0, stream>>>(G1, G2, Wp, bp, (float*)d_out);
}

// Round 3
// 576.127 us; speedup vs baseline: 1.8208x; 1.1343x over previous
//
#include <hip/hip_runtime.h>

// Problem constants (fixed by reference)
#define NN 50000      // nodes
#define NE 800000     // edges
#define DD 256        // node feat dim
#define GFEAT 200     // graph feat dim
#define NG 512        // graphs

typedef __bf16 bf16;
typedef bf16 bf16x4 __attribute__((ext_vector_type(4)));
typedef bf16 bf16x8 __attribute__((ext_vector_type(8)));
typedef float f32x4 __attribute__((ext_vector_type(4)));

// async global->LDS, 16B per lane. HW dest = wave-uniform base + lane*16.
__device__ __forceinline__ void gl_lds16(const bf16* g, bf16* l) {
    __builtin_amdgcn_global_load_lds(
        (const __attribute__((address_space(1))) uint32_t*)(g),
        (__attribute__((address_space(3))) uint32_t*)(l), 16, 0, 0);
}

// swizzled fragment read: LDS [row][32k] where chunk c holds global chunk c^((row>>1)&3)
__device__ __forceinline__ bf16x8 frag_ld(const bf16* s, int R, int C) {
    return *(const bf16x8*)&s[R * 32 + ((C ^ ((R >> 1) & 3)) << 3)];
}

#define EPI_STRIDE 136   // bf16 elems; 272 B row stride (16B-aligned, bank-shift 4/row)

// ---------------------------------------------------------------------------
// conversions
// ---------------------------------------------------------------------------
__global__ __launch_bounds__(256) void conv_x2_kernel(const float* __restrict__ in0,
                                                      const float* __restrict__ in1,
                                                      bf16* __restrict__ out0,
                                                      bf16* __restrict__ out1, int n4) {
    const float* in = blockIdx.y ? in1 : in0;
    bf16* out = blockIdx.y ? out1 : out0;
    int i = blockIdx.x * 256 + threadIdx.x;
    if (i < n4) {
        float4 v = ((const float4*)in)[i];
        bf16x4 o;
        o[0] = (bf16)v.x; o[1] = (bf16)v.y; o[2] = (bf16)v.z; o[3] = (bf16)v.w;
        ((bf16x4*)out)[i] = o;
    }
}

// 8 weight matrices fp32 [K][N] -> bf16 [256][256] = [n][k] transposed, zero-padded.
__global__ __launch_bounds__(256) void conv_w8_kernel(
    const float* __restrict__ w0, const float* __restrict__ w1,
    const float* __restrict__ w2, const float* __restrict__ w3,
    const float* __restrict__ w4, const float* __restrict__ w5,
    const float* __restrict__ w6, const float* __restrict__ w7,
    bf16* __restrict__ out_base) {
    const float* ws[8] = {w0, w1, w2, w3, w4, w5, w6, w7};
    const int Ns[8] = {DD, DD, DD, GFEAT, DD, DD, DD, GFEAT};
    int m = blockIdx.y;
    const float* in = ws[m];
    int N = Ns[m];
    int idx = blockIdx.x * 256 + threadIdx.x;   // 0..65535 over [n][k]
    int n = idx >> 8, k = idx & 255;
    float v = (n < N) ? in[k * N + n] : 0.f;
    out_base[(size_t)m * 65536 + idx] = (bf16)v;
}

// ---------------------------------------------------------------------------
// CSR build: two-level counting sort, zero global atomics, O(1) reads/edge.
// ---------------------------------------------------------------------------
#define NBKT   128
#define NPB    391            // ceil(NN / NBKT); 128*391 = 50048
#define NCHUNK 256
#define CE     ((NE + NCHUNK - 1) / NCHUNK)   // 3125 edges per chunk

__global__ __launch_bounds__(256) void csr_coarse_hist_kernel(
    const int* __restrict__ d0, const int* __restrict__ d1,
    int* __restrict__ cnt0, int* __restrict__ cnt1) {
    const int blk = blockIdx.x, t = threadIdx.x;
    const int* dst = blockIdx.y ? d1 : d0;
    int* cnt = blockIdx.y ? cnt1 : cnt0;
    __shared__ int hist[NBKT];
    if (t < NBKT) hist[t] = 0;
    __syncthreads();
    const int e0 = blk * CE;
    const int e1 = (e0 + CE < NE) ? e0 + CE : NE;
    for (int e = e0 + t; e < e1; e += 256)
        atomicAdd(&hist[dst[e] / NPB], 1);
    __syncthreads();
    if (t < NBKT) cnt[t * NCHUNK + blk] = hist[t];   // bucket-major
}

__global__ __launch_bounds__(1024) void csr_scan_kernel(
    int* __restrict__ cnt0, int* __restrict__ cnt1,
    int* __restrict__ offs0, int* __restrict__ offs1) {
    int* cnt = blockIdx.y ? cnt1 : cnt0;
    const int t = threadIdx.x;
    const int PER = (NBKT * NCHUNK) / 1024;   // 32
    int v[PER];
    int sum = 0;
    const int base = t * PER;
#pragma unroll
    for (int i = 0; i < PER; i += 4) {
        int4 q = *(const int4*)&cnt[base + i];
        v[i] = q.x; v[i + 1] = q.y; v[i + 2] = q.z; v[i + 3] = q.w;
        sum += q.x + q.y + q.z + q.w;
    }
    __shared__ int s[1024];
    s[t] = sum;
    __syncthreads();
    for (int off = 1; off < 1024; off <<= 1) {
        int a = (t >= off) ? s[t - off] : 0;
        __syncthreads();
        s[t] += a;
        __syncthreads();
    }
    int run = s[t] - sum;   // exclusive prefix of this thread's chunk
#pragma unroll
    for (int i = 0; i < PER; i++) { int c = v[i]; cnt[base + i] = run; run += c; }
    if (t == 0) (blockIdx.y ? offs1 : offs0)[NN] = NE;
}

__global__ __launch_bounds__(256) void csr_partition_kernel(
    const int* __restrict__ sA, const int* __restrict__ sB,
    const int* __restrict__ d0, const int* __restrict__ d1,
    const int* __restrict__ cnt0, const int* __restrict__ cnt1,
    int2* __restrict__ eb0, int2* __restrict__ eb1) {
    const int blk = blockIdx.x, t = threadIdx.x;
    const int* src = blockIdx.y ? sB : sA;
    const int* dst = blockIdx.y ? d1 : d0;
    const int* cnt = blockIdx.y ? cnt1 : cnt0;
    int2* eb = blockIdx.y ? eb1 : eb0;
    __shared__ int cur[NBKT];
    if (t < NBKT) cur[t] = cnt[t * NCHUNK + blk];   // this chunk's start in each bucket
    __syncthreads();
    const int e0 = blk * CE;
    const int e1 = (e0 + CE < NE) ? e0 + CE : NE;
    for (int e = e0 + t; e < e1; e += 256) {
        int d = dst[e], s = src[e];
        int pos = atomicAdd(&cur[d / NPB], 1);      // LDS atomic, range disjoint per block
        eb[pos] = make_int2(s, d);
    }
}

__global__ __launch_bounds__(512) void csr_bucket_sort_kernel(
    const int* __restrict__ cnt0, const int* __restrict__ cnt1,
    const int2* __restrict__ eb0, const int2* __restrict__ eb1,
    int* __restrict__ offs0, int* __restrict__ offs1,
    int* __restrict__ csr0, int* __restrict__ csr1) {
    const int b = blockIdx.x, t = threadIdx.x;
    const int* cnt = blockIdx.y ? cnt1 : cnt0;
    const int2* eb = blockIdx.y ? eb1 : eb0;
    int* offs = blockIdx.y ? offs1 : offs0;
    int* csr = blockIdx.y ? csr1 : csr0;
    const int lo = b * NPB;
    const int ncnt = (NN - lo < NPB) ? (NN - lo) : NPB;
    const int beg = cnt[b * NCHUNK];
    const int end = (b == NBKT - 1) ? NE : cnt[(b + 1) * NCHUNK];

    __shared__ int hist[NPB];
    __shared__ int s[512];
    if (t < NPB) hist[t] = 0;
    __syncthreads();
    for (int i = beg + t; i < end; i += 512)
        atomicAdd(&hist[eb[i].y - lo], 1);
    __syncthreads();

    int h = (t < NPB) ? hist[t] : 0;
    s[t] = h;
    __syncthreads();
    for (int off = 1; off < 512; off <<= 1) {
        int a = (t >= off) ? s[t - off] : 0;
        __syncthreads();
        s[t] += a;
        __syncthreads();
    }
    int excl = s[t] - h;
    __syncthreads();
    if (t < NPB) hist[t] = excl;                 // local cursors
    if (t < ncnt) offs[lo + t] = beg + excl;     // final global offsets
    __syncthreads();

    for (int i = beg + t; i < end; i += 512) {
        int2 v = eb[i];
        int pos = atomicAdd(&hist[v.y - lo], 1);
        csr[beg + pos] = v.x;                    // contiguous ~25 KB region per block
    }
}

// ---------------------------------------------------------------------------
// bf16 MFMA GEMM, BOTH BRANCHES (blockIdx.y), K=256 fixed, out width 256.
// XCD-swizzled block decode: all col-blocks of one row-panel share id mod 8
// -> same XCD -> A panel fetched once per XCD (round-robin dispatch).
// Generic: 2 col-blocks (256 cols). grid (49*16, 2).
// ---------------------------------------------------------------------------
__global__ __launch_bounds__(256) void mfma_gemm2_kernel(
    const bf16* __restrict__ A0, const bf16* __restrict__ A1,
    const bf16* __restrict__ Bt0, const bf16* __restrict__ Bt1,
    const float* __restrict__ bias0, const float* __restrict__ bias1,
    bf16* __restrict__ out0, bf16* __restrict__ out1,
    int M, int Nb, int do_relu) {
    const int lid = blockIdx.x;
    const int r8 = lid & 7, cc = (lid >> 3) & 1, g = lid >> 4;
    const int row_blk = g * 8 + r8;
    if (row_blk * 128 >= M) return;
    const bf16* A = blockIdx.y ? A1 : A0;
    const bf16* Bt = blockIdx.y ? Bt1 : Bt0;
    const float* bias = blockIdx.y ? bias1 : bias0;
    bf16* out = blockIdx.y ? out1 : out0;

    __shared__ bf16 smem[16384];
    bf16* As = smem;
    bf16* Bs = smem + 8192;

    const int t    = threadIdx.x;
    const int lane = t & 63;
    const int w    = t >> 6;
    const int row0 = row_blk * 128;
    const int col0 = cc * 128;

    f32x4 acc[4][4] = {};
    const int wm = (w >> 1) * 64, wn = (w & 1) * 64;
    const int fm = lane & 15, fC = lane >> 4;

    for (int k0 = 0; k0 < 256; k0 += 32) {
#pragma unroll
        for (int r = 0; r < 2; r++) {
            int flat = r * 256 + t;
            int fr = flat >> 2, fc = flat & 3;
            int fcg = fc ^ ((fr >> 1) & 3);          // swizzle
            int arow = row0 + fr;
            if (arow > M - 1) arow = M - 1;
            gl_lds16(&A[(size_t)arow * 256 + k0 + fcg * 8], &As[flat * 8]);
        }
#pragma unroll
        for (int r = 0; r < 2; r++) {
            int flat = r * 256 + t;
            int fr = flat >> 2, fc = flat & 3;
            int fcg = fc ^ ((fr >> 1) & 3);
            int brow = col0 + fr;                    // Bt padded to 256 rows
            gl_lds16(&Bt[(size_t)brow * 256 + k0 + fcg * 8], &Bs[flat * 8]);
        }
        __syncthreads();

        bf16x8 af[4], bfr[4];
#pragma unroll
        for (int i = 0; i < 4; i++) af[i] = frag_ld(As, wm + i * 16 + fm, fC);
#pragma unroll
        for (int i = 0; i < 4; i++) bfr[i] = frag_ld(Bs, wn + i * 16 + fm, fC);
#pragma unroll
        for (int i = 0; i < 4; i++)
#pragma unroll
            for (int j = 0; j < 4; j++)
                acc[i][j] = __builtin_amdgcn_mfma_f32_16x16x32_bf16(af[i], bfr[j], acc[i][j], 0, 0, 0);
        __syncthreads();
    }

    float bv[4];
#pragma unroll
    for (int j = 0; j < 4; j++) {
        int col = col0 + wn + fm + j * 16;
        bv[j] = (col < Nb) ? bias[col] : 0.f;
    }

#pragma unroll
    for (int p = 0; p < 2; p++) {
        if ((w >> 1) == p) {
#pragma unroll
            for (int i = 0; i < 4; i++)
#pragma unroll
                for (int j = 0; j < 4; j++)
#pragma unroll
                    for (int r2 = 0; r2 < 4; r2++) {
                        int rl = i * 16 + (lane >> 4) * 4 + r2;   // 0..63
                        int cl = wn + fm + j * 16;                // 0..127
                        float v = acc[i][j][r2] + bv[j];
                        if (do_relu) v = fmaxf(v, 0.f);
                        smem[rl * EPI_STRIDE + cl] = (bf16)v;
                    }
        }
        __syncthreads();
#pragma unroll
        for (int q = 0; q < 4; q++) {
            int flat = q * 256 + t;
            int rl = flat >> 4, seg = flat & 15;
            int grow = row0 + p * 64 + rl;
            if (grow < M)
                *(bf16x8*)&out[(size_t)grow * 256 + col0 + seg * 8] =
                    *(const bf16x8*)&smem[rl * EPI_STRIDE + seg * 8];
        }
        __syncthreads();
    }
}

// Fused W+Wr GEMM, both branches. Bt2 is 512x256: cols 0-255 -> out_lo (no act),
// 256-511 -> out_hi = relu(.+bias_hi). 4 col-blocks. grid (49*32, 2).
__global__ __launch_bounds__(256) void mfma_gemm_fused2_kernel(
    const bf16* __restrict__ A0, const bf16* __restrict__ A1,
    const bf16* __restrict__ Bt2_0, const bf16* __restrict__ Bt2_1,
    const float* __restrict__ bh0, const float* __restrict__ bh1,
    bf16* __restrict__ lo0, bf16* __restrict__ lo1,
    bf16* __restrict__ hi0, bf16* __restrict__ hi1, int M) {
    const int lid = blockIdx.x;
    const int r8 = lid & 7, cc = (lid >> 3) & 3, g = lid >> 5;
    const int row_blk = g * 8 + r8;
    if (row_blk * 128 >= M) return;
    const bf16* A = blockIdx.y ? A1 : A0;
    const bf16* Bt2 = blockIdx.y ? Bt2_1 : Bt2_0;
    const float* bias_hi = blockIdx.y ? bh1 : bh0;
    bf16* out_lo = blockIdx.y ? lo1 : lo0;
    bf16* out_hi = blockIdx.y ? hi1 : hi0;

    __shared__ bf16 smem[16384];
    bf16* As = smem;
    bf16* Bs = smem + 8192;

    const int t    = threadIdx.x;
    const int lane = t & 63;
    const int w    = t >> 6;
    const int row0 = row_blk * 128;
    const int col0 = cc * 128;   // 0..384

    f32x4 acc[4][4] = {};
    const int wm = (w >> 1) * 64, wn = (w & 1) * 64;
    const int fm = lane & 15, fC = lane >> 4;

    for (int k0 = 0; k0 < 256; k0 += 32) {
#pragma unroll
        for (int r = 0; r < 2; r++) {
            int flat = r * 256 + t;
            int fr = flat >> 2, fc = flat & 3;
            int fcg = fc ^ ((fr >> 1) & 3);
            int arow = row0 + fr;
            if (arow > M - 1) arow = M - 1;
            gl_lds16(&A[(size_t)arow * 256 + k0 + fcg * 8], &As[flat * 8]);
        }
#pragma unroll
        for (int r = 0; r < 2; r++) {
            int flat = r * 256 + t;
            int fr = flat >> 2, fc = flat & 3;
            int fcg = fc ^ ((fr >> 1) & 3);
            int brow = col0 + fr;
            gl_lds16(&Bt2[(size_t)brow * 256 + k0 + fcg * 8], &Bs[flat * 8]);
        }
        __syncthreads();

        bf16x8 af[4], bfr[4];
#pragma unroll
        for (int i = 0; i < 4; i++) af[i] = frag_ld(As, wm + i * 16 + fm, fC);
#pragma unroll
        for (int i = 0; i < 4; i++) bfr[i] = frag_ld(Bs, wn + i * 16 + fm, fC);
#pragma unroll
        for (int i = 0; i < 4; i++)
#pragma unroll
            for (int j = 0; j < 4; j++)
                acc[i][j] = __builtin_amdgcn_mfma_f32_16x16x32_bf16(af[i], bfr[j], acc[i][j], 0, 0, 0);
        __syncthreads();
    }

    const bool hi = (col0 >= 256);          // block-uniform
    bf16* out = hi ? out_hi : out_lo;
    const int cb = hi ? col0 - 256 : col0;

    float bv[4];
#pragma unroll
    for (int j = 0; j < 4; j++) {
        int col = cb + wn + fm + j * 16;
        bv[j] = hi ? bias_hi[col] : 0.f;
    }

#pragma unroll
    for (int p = 0; p < 2; p++) {
        if ((w >> 1) == p) {
#pragma unroll
            for (int i = 0; i < 4; i++)
#pragma unroll
                for (int j = 0; j < 4; j++)
#pragma unroll
                    for (int r2 = 0; r2 < 4; r2++) {
                        int rl = i * 16 + (lane >> 4) * 4 + r2;
                        int cl = wn + fm + j * 16;
                        float v = acc[i][j][r2] + bv[j];
                        if (hi) v = fmaxf(v, 0.f);
                        smem[rl * EPI_STRIDE + cl] = (bf16)v;
                    }
        }
        __syncthreads();
#pragma unroll
        for (int q = 0; q < 4; q++) {
            int flat = q * 256 + t;
            int rl = flat >> 4, seg = flat & 15;
            int grow = row0 + p * 64 + rl;
            if (grow < M)
                *(bf16x8*)&out[(size_t)grow * 256 + cb + seg * 8] =
                    *(const bf16x8*)&smem[rl * EPI_STRIDE + seg * 8];
        }
        __syncthreads();
    }
}

// ---------------------------------------------------------------------------
// edge aggregation + combine, both branches (blockIdx.y), 4 gathers in flight:
// H[v] = relu(sum_{e: dst=v} hW[src[e]] + b) + res[v]
// one wave per dst node; lane covers 8 feats (16B), half-waves cover edges.
// ---------------------------------------------------------------------------
__global__ __launch_bounds__(256) void agg_combine2_kernel(
    const bf16* __restrict__ hW0, const bf16* __restrict__ hW1,
    const int* __restrict__ csr0, const int* __restrict__ csr1,
    const int* __restrict__ offs0, const int* __restrict__ offs1,
    const float* __restrict__ bias0, const float* __restrict__ bias1,
    const bf16* __restrict__ res0, const bf16* __restrict__ res1,
    bf16* __restrict__ H0, bf16* __restrict__ H1, int n_nodes) {
    const bf16* hW = blockIdx.y ? hW1 : hW0;
    const int* csr_src = blockIdx.y ? csr1 : csr0;
    const int* offsets = blockIdx.y ? offs1 : offs0;
    const float* bias = blockIdx.y ? bias1 : bias0;
    const bf16* res = blockIdx.y ? res1 : res0;
    bf16* H = blockIdx.y ? H1 : H0;

    int wave = threadIdx.x >> 6;
    int lane = threadIdx.x & 63;
    int node = blockIdx.x * 4 + wave;
    if (node >= n_nodes) return;
    int beg = offsets[node], end = offsets[node + 1];
    const int half = lane >> 5;
    const int fo   = (lane & 31) * 8;

    float acc[8] = {};
    int j = beg;
    // 8 edges per iteration; half h covers {j+h, j+2+h, j+4+h, j+6+h}
    for (; j + 6 + half < end; j += 8) {
        int s0 = csr_src[j + half];
        int s1 = csr_src[j + 2 + half];
        int s2 = csr_src[j + 4 + half];
        int s3 = csr_src[j + 6 + half];
        bf16x8 v0 = *(const bf16x8*)&hW[(size_t)s0 * DD + fo];
        bf16x8 v1 = *(const bf16x8*)&hW[(size_t)s1 * DD + fo];
        bf16x8 v2 = *(const bf16x8*)&hW[(size_t)s2 * DD + fo];
        bf16x8 v3 = *(const bf16x8*)&hW[(size_t)s3 * DD + fo];
#pragma unroll
        for (int q = 0; q < 8; q++) acc[q] += (float)v0[q];
#pragma unroll
        for (int q = 0; q < 8; q++) acc[q] += (float)v1[q];
#pragma unroll
        for (int q = 0; q < 8; q++) acc[q] += (float)v2[q];
#pragma unroll
        for (int q = 0; q < 8; q++) acc[q] += (float)v3[q];
    }
    for (; j + half < end; j += 2) {
        int s = csr_src[j + half];
        bf16x8 v = *(const bf16x8*)&hW[(size_t)s * DD + fo];
#pragma unroll
        for (int q = 0; q < 8; q++) acc[q] += (float)v[q];
    }
#pragma unroll
    for (int q = 0; q < 8; q++) acc[q] += __shfl_xor(acc[q], 32, 64);

    if (half == 0) {
        float4 b0 = *(const float4*)&bias[fo];
        float4 b1 = *(const float4*)&bias[fo + 4];
        bf16x8 rv = *(const bf16x8*)&res[(size_t)node * DD + fo];
        bf16x8 o;
        o[0] = (bf16)(fmaxf(acc[0] + b0.x, 0.f) + (float)rv[0]);
        o[1] = (bf16)(fmaxf(acc[1] + b0.y, 0.f) + (float)rv[1]);
        o[2] = (bf16)(fmaxf(acc[2] + b0.z, 0.f) + (float)rv[2]);
        o[3] = (bf16)(fmaxf(acc[3] + b0.w, 0.f) + (float)rv[3]);
        o[4] = (bf16)(fmaxf(acc[4] + b1.x, 0.f) + (float)rv[4]);
        o[5] = (bf16)(fmaxf(acc[5] + b1.y, 0.f) + (float)rv[5]);
        o[6] = (bf16)(fmaxf(acc[6] + b1.z, 0.f) + (float)rv[6]);
        o[7] = (bf16)(fmaxf(acc[7] + b1.w, 0.f) + (float)rv[7]);
        *(bf16x8*)&H[(size_t)node * DD + fo] = o;
    }
}

// ---------------------------------------------------------------------------
// per-graph segment sum of P[N_nodes, 256(stride)] bf16, cols<GFEAT; both branches
// ---------------------------------------------------------------------------
__global__ __launch_bounds__(256) void graph_reduce2_kernel(
    const bf16* __restrict__ P0, const bf16* __restrict__ P1,
    const int* __restrict__ g0, const int* __restrict__ g1,
    float* __restrict__ G0, float* __restrict__ G1, int n_nodes) {
    const bf16* P = blockIdx.y ? P1 : P0;
    const int* gids = blockIdx.y ? g1 : g0;
    float* G = blockIdx.y ? G1 : G0;

    int g = blockIdx.x;
    int lo = 0, hi = n_nodes;
    while (lo < hi) { int mid = (lo + hi) >> 1; if (gids[mid] < g) lo = mid + 1; else hi = mid; }
    int beg = lo;
    hi = n_nodes;
    while (lo < hi) { int mid = (lo + hi) >> 1; if (gids[mid] < g + 1) lo = mid + 1; else hi = mid; }
    int end = lo;

    int c = threadIdx.x;
    if (c < GFEAT) {
        float acc = 0.f;
        for (int r = beg; r < end; r++) acc += (float)P[(size_t)r * 256 + c];
        G[(size_t)g * GFEAT + c] = acc;
    }
}

__global__ __launch_bounds__(256) void predictor_kernel(const float* __restrict__ G1,
                                                        const float* __restrict__ G2,
                                                        const float* __restrict__ Wp,
                                                        const float* __restrict__ bp,
                                                        float* __restrict__ out) {
    int i = blockIdx.x * 256 + threadIdx.x;
    if (i >= NG) return;
    float acc = bp[0];
    for (int f = 0; f < GFEAT; f++)
        acc += (G1[i * GFEAT + f] + G2[i * GFEAT + f]) * Wp[f];
    out[i] = acc;
}

extern "C" void kernel_launch(void* const* d_in, const int* in_sizes, int n_in,
                              void* d_out, int out_size, void* d_ws, size_t ws_size,
                              hipStream_t stream) {
    const float* X1   = (const float*)d_in[0];
    const float* X2   = (const float*)d_in[2];
    const int*   src1 = (const int*)d_in[4];
    const int*   dst1 = (const int*)d_in[5];
    const int*   gid1 = (const int*)d_in[6];
    const int*   src2 = (const int*)d_in[7];
    const int*   dst2 = (const int*)d_in[8];
    const int*   gid2 = (const int*)d_in[9];
    const float* W1  = (const float*)d_in[10]; const float* b1  = (const float*)d_in[11];
    const float* Wr1 = (const float*)d_in[12]; const float* br1 = (const float*)d_in[13];
    const float* W2  = (const float*)d_in[14]; const float* b2  = (const float*)d_in[15];
    const float* Wr2 = (const float*)d_in[16]; const float* br2 = (const float*)d_in[17];
    const float* Ri1 = (const float*)d_in[18]; const float* rbi1 = (const float*)d_in[19];
    const float* Ro1 = (const float*)d_in[20]; const float* rbo1 = (const float*)d_in[21];
    const float* Ri2 = (const float*)d_in[22]; const float* rbi2 = (const float*)d_in[23];
    const float* Ro2 = (const float*)d_in[24]; const float* rbo2 = (const float*)d_in[25];
    const float* Wp  = (const float*)d_in[26]; const float* bp  = (const float*)d_in[27];

    // workspace layout (per-branch buffers; lifetime-disjoint aliases)
    const size_t NB = (size_t)NN * DD * sizeof(bf16);   // 25.6 MB
    char* p = (char*)d_ws;
    bf16* XbH1 = (bf16*)p; p += NB;     // Xb1 (conv->fused), then H1 (agg->Ri)
    bf16* XbH2 = (bf16*)p; p += NB;
    bf16* hWR1 = (bf16*)p; p += NB;     // eb1 (CSR), then hW1 (fused->agg), then R1 (Ri->Ro)
    bf16* hWR2 = (bf16*)p; p += NB;
    bf16* resP1 = (bf16*)p; p += NB;    // res1 (fused->agg), then P1 (Ro->reduce)
    bf16* resP2 = (bf16*)p; p += NB;
    float* G1  = (float*)p; p += (size_t)NG * GFEAT * sizeof(float);
    float* G2  = (float*)p; p += (size_t)NG * GFEAT * sizeof(float);
    // 8 weight mats; order: W1,Wr1,Ri1,Ro1,W2,Wr2,Ri2,Ro2 (W|Wr contiguous = fused Bt)
    bf16* Wbase = (bf16*)p; p += 8 * 65536 * sizeof(bf16);
    int* offs1 = (int*)p; p += (NN + 1) * sizeof(int);
    int* offs2 = (int*)p; p += (NN + 1) * sizeof(int);
    int* cnt1  = (int*)p; p += NBKT * NCHUNK * sizeof(int);
    int* cnt2  = (int*)p; p += NBKT * NCHUNK * sizeof(int);
    int* csr1  = (int*)p; p += NE * sizeof(int);
    int* csr2  = (int*)p; p += NE * sizeof(int);
    int2* eb1 = (int2*)hWR1;   // live only during CSR build (before fused writes hW)
    int2* eb2 = (int2*)hWR2;

    conv_w8_kernel<<<dim3(256, 8), 256, 0, stream>>>(W1, Wr1, Ri1, Ro1, W2, Wr2, Ri2, Ro2, Wbase);
    conv_x2_kernel<<<dim3((NN * DD / 4 + 255) / 256, 2), 256, 0, stream>>>(
        X1, X2, XbH1, XbH2, NN * DD / 4);

    // CSR build (both branches): two-level counting sort, no global atomics
    csr_coarse_hist_kernel<<<dim3(NCHUNK, 2), 256, 0, stream>>>(dst1, dst2, cnt1, cnt2);
    csr_scan_kernel<<<dim3(1, 2), 1024, 0, stream>>>(cnt1, cnt2, offs1, offs2);
    csr_partition_kernel<<<dim3(NCHUNK, 2), 256, 0, stream>>>(
        src1, src2, dst1, dst2, cnt1, cnt2, eb1, eb2);
    csr_bucket_sort_kernel<<<dim3(NBKT, 2), 512, 0, stream>>>(
        cnt1, cnt2, eb1, eb2, offs1, offs2, csr1, csr2);

    // hW = X @ W ; res = relu(X @ Wr + br)          [both branches]
    mfma_gemm_fused2_kernel<<<dim3(49 * 32, 2), 256, 0, stream>>>(
        XbH1, XbH2, Wbase + 0 * 65536, Wbase + 4 * 65536, br1, br2,
        hWR1, hWR2, resP1, resP2, NN);
    // H = relu(agg + b) + res                       [both branches]
    agg_combine2_kernel<<<dim3((NN + 3) / 4, 2), 256, 0, stream>>>(
        hWR1, hWR2, csr1, csr2, offs1, offs2, b1, b2, resP1, resP2, XbH1, XbH2, NN);
    // R = relu(H @ Ri + rbi)                        [both branches]
    mfma_gemm2_kernel<<<dim3(49 * 16, 2), 256, 0, stream>>>(
        XbH1, XbH2, Wbase + 2 * 65536, Wbase + 6 * 65536, rbi1, rbi2,
        hWR1, hWR2, NN, DD, 1);
    // P = R @ Ro + rbo (bf16, stride 256, cols<200) [both branches]
    mfma_gemm2_kernel<<<dim3(49 * 16, 2), 256, 0, stream>>>(
        hWR1, hWR2, Wbase + 3 * 65536, Wbase + 7 * 65536, rbo1, rbo2,
        resP1, resP2, NN, GFEAT, 0);
    // G = segment_sum(P, gids)                      [both branches]
    graph_reduce2_kernel<<<dim3(NG, 2), 256, 0, stream>>>(
        resP1, resP2, gid1, gid2, G1, G2, NN);

    predictor_kernel<<<(NG + 255) / 256, 256, 0, stream>>>(G1, G2, Wp, bp, (float*)d_out);
}

// Round 4
// 572.612 us; speedup vs baseline: 1.8320x; 1.0061x over previous
//
#include <hip/hip_runtime.h>

// Problem constants (fixed by reference)
#define NN 50000      // nodes
#define NE 800000     // edges
#define DD 256        // node feat dim
#define GFEAT 200     // graph feat dim
#define NG 512        // graphs

typedef __bf16 bf16;
typedef bf16 bf16x4 __attribute__((ext_vector_type(4)));
typedef bf16 bf16x8 __attribute__((ext_vector_type(8)));
typedef float f32x4 __attribute__((ext_vector_type(4)));

// async global->LDS, 16B per lane. HW dest = wave-uniform base + lane*16.
__device__ __forceinline__ void gl_lds16(const bf16* g, bf16* l) {
    __builtin_amdgcn_global_load_lds(
        (const __attribute__((address_space(1))) uint32_t*)(g),
        (__attribute__((address_space(3))) uint32_t*)(l), 16, 0, 0);
}

// swizzled fragment read: LDS [row][32k] where chunk c holds global chunk c^((row>>1)&3)
__device__ __forceinline__ bf16x8 frag_ld(const bf16* s, int R, int C) {
    return *(const bf16x8*)&s[R * 32 + ((C ^ ((R >> 1) & 3)) << 3)];
}

#define EPI_STRIDE 136   // bf16 elems; 272 B row stride (16B-aligned, bank-shift 4/row)

// ---------------------------------------------------------------------------
// conversions
// ---------------------------------------------------------------------------
__global__ __launch_bounds__(256) void conv_x2_kernel(const float* __restrict__ in0,
                                                      const float* __restrict__ in1,
                                                      bf16* __restrict__ out0,
                                                      bf16* __restrict__ out1, int n4) {
    const float* in = blockIdx.y ? in1 : in0;
    bf16* out = blockIdx.y ? out1 : out0;
    int i = blockIdx.x * 256 + threadIdx.x;
    if (i < n4) {
        float4 v = ((const float4*)in)[i];
        bf16x4 o;
        o[0] = (bf16)v.x; o[1] = (bf16)v.y; o[2] = (bf16)v.z; o[3] = (bf16)v.w;
        ((bf16x4*)out)[i] = o;
    }
}

// 8 weight matrices fp32 [K][N] -> bf16 [256][256] = [n][k] transposed, zero-padded.
__global__ __launch_bounds__(256) void conv_w8_kernel(
    const float* __restrict__ w0, const float* __restrict__ w1,
    const float* __restrict__ w2, const float* __restrict__ w3,
    const float* __restrict__ w4, const float* __restrict__ w5,
    const float* __restrict__ w6, const float* __restrict__ w7,
    bf16* __restrict__ out_base) {
    const float* ws[8] = {w0, w1, w2, w3, w4, w5, w6, w7};
    const int Ns[8] = {DD, DD, DD, GFEAT, DD, DD, DD, GFEAT};
    int m = blockIdx.y;
    const float* in = ws[m];
    int N = Ns[m];
    int idx = blockIdx.x * 256 + threadIdx.x;   // 0..65535 over [n][k]
    int n = idx >> 8, k = idx & 255;
    float v = (n < N) ? in[k * N + n] : 0.f;
    out_base[(size_t)m * 65536 + idx] = (bf16)v;
}

// ---------------------------------------------------------------------------
// CSR build: two-level counting sort, zero global atomics, O(1) reads/edge.
// ---------------------------------------------------------------------------
#define NBKT   128
#define NPB    391            // ceil(NN / NBKT); 128*391 = 50048
#define NCHUNK 256
#define CE     ((NE + NCHUNK - 1) / NCHUNK)   // 3125 edges per chunk

__global__ __launch_bounds__(256) void csr_coarse_hist_kernel(
    const int* __restrict__ d0, const int* __restrict__ d1,
    int* __restrict__ cnt0, int* __restrict__ cnt1) {
    const int blk = blockIdx.x, t = threadIdx.x;
    const int* dst = blockIdx.y ? d1 : d0;
    int* cnt = blockIdx.y ? cnt1 : cnt0;
    __shared__ int hist[NBKT];
    if (t < NBKT) hist[t] = 0;
    __syncthreads();
    const int e0 = blk * CE;
    const int e1 = (e0 + CE < NE) ? e0 + CE : NE;
    for (int e = e0 + t; e < e1; e += 256)
        atomicAdd(&hist[dst[e] / NPB], 1);
    __syncthreads();
    if (t < NBKT) cnt[t * NCHUNK + blk] = hist[t];   // bucket-major
}

__global__ __launch_bounds__(1024) void csr_scan_kernel(
    int* __restrict__ cnt0, int* __restrict__ cnt1,
    int* __restrict__ offs0, int* __restrict__ offs1) {
    int* cnt = blockIdx.y ? cnt1 : cnt0;
    const int t = threadIdx.x;
    const int PER = (NBKT * NCHUNK) / 1024;   // 32
    int v[PER];
    int sum = 0;
    const int base = t * PER;
#pragma unroll
    for (int i = 0; i < PER; i += 4) {
        int4 q = *(const int4*)&cnt[base + i];
        v[i] = q.x; v[i + 1] = q.y; v[i + 2] = q.z; v[i + 3] = q.w;
        sum += q.x + q.y + q.z + q.w;
    }
    __shared__ int s[1024];
    s[t] = sum;
    __syncthreads();
    for (int off = 1; off < 1024; off <<= 1) {
        int a = (t >= off) ? s[t - off] : 0;
        __syncthreads();
        s[t] += a;
        __syncthreads();
    }
    int run = s[t] - sum;   // exclusive prefix of this thread's chunk
#pragma unroll
    for (int i = 0; i < PER; i++) { int c = v[i]; cnt[base + i] = run; run += c; }
    if (t == 0) (blockIdx.y ? offs1 : offs0)[NN] = NE;
}

__global__ __launch_bounds__(256) void csr_partition_kernel(
    const int* __restrict__ sA, const int* __restrict__ sB,
    const int* __restrict__ d0, const int* __restrict__ d1,
    const int* __restrict__ cnt0, const int* __restrict__ cnt1,
    int2* __restrict__ eb0, int2* __restrict__ eb1) {
    const int blk = blockIdx.x, t = threadIdx.x;
    const int* src = blockIdx.y ? sB : sA;
    const int* dst = blockIdx.y ? d1 : d0;
    const int* cnt = blockIdx.y ? cnt1 : cnt0;
    int2* eb = blockIdx.y ? eb1 : eb0;
    __shared__ int cur[NBKT];
    if (t < NBKT) cur[t] = cnt[t * NCHUNK + blk];   // this chunk's start in each bucket
    __syncthreads();
    const int e0 = blk * CE;
    const int e1 = (e0 + CE < NE) ? e0 + CE : NE;
    for (int e = e0 + t; e < e1; e += 256) {
        int d = dst[e], s = src[e];
        int pos = atomicAdd(&cur[d / NPB], 1);      // LDS atomic, range disjoint per block
        eb[pos] = make_int2(s, d);
    }
}

__global__ __launch_bounds__(512) void csr_bucket_sort_kernel(
    const int* __restrict__ cnt0, const int* __restrict__ cnt1,
    const int2* __restrict__ eb0, const int2* __restrict__ eb1,
    int* __restrict__ offs0, int* __restrict__ offs1,
    int* __restrict__ csr0, int* __restrict__ csr1) {
    const int b = blockIdx.x, t = threadIdx.x;
    const int* cnt = blockIdx.y ? cnt1 : cnt0;
    const int2* eb = blockIdx.y ? eb1 : eb0;
    int* offs = blockIdx.y ? offs1 : offs0;
    int* csr = blockIdx.y ? csr1 : csr0;
    const int lo = b * NPB;
    const int ncnt = (NN - lo < NPB) ? (NN - lo) : NPB;
    const int beg = cnt[b * NCHUNK];
    const int end = (b == NBKT - 1) ? NE : cnt[(b + 1) * NCHUNK];

    __shared__ int hist[NPB];
    __shared__ int s[512];
    if (t < NPB) hist[t] = 0;
    __syncthreads();
    for (int i = beg + t; i < end; i += 512)
        atomicAdd(&hist[eb[i].y - lo], 1);
    __syncthreads();

    int h = (t < NPB) ? hist[t] : 0;
    s[t] = h;
    __syncthreads();
    for (int off = 1; off < 512; off <<= 1) {
        int a = (t >= off) ? s[t - off] : 0;
        __syncthreads();
        s[t] += a;
        __syncthreads();
    }
    int excl = s[t] - h;
    __syncthreads();
    if (t < NPB) hist[t] = excl;                 // local cursors
    if (t < ncnt) offs[lo + t] = beg + excl;     // final global offsets
    __syncthreads();

    for (int i = beg + t; i < end; i += 512) {
        int2 v = eb[i];
        int pos = atomicAdd(&hist[v.y - lo], 1);
        csr[beg + pos] = v.x;                    // contiguous ~25 KB region per block
    }
}

// ---------------------------------------------------------------------------
// bf16 MFMA GEMM, BOTH BRANCHES (blockIdx.y), K=256 fixed, out width 256.
// XCD-swizzled block decode: all col-blocks of one row-panel share id mod 8
// -> same XCD -> A panel fetched once per XCD (round-robin dispatch).
// Generic: 2 col-blocks (256 cols). grid (49*16, 2).
// ---------------------------------------------------------------------------
__global__ __launch_bounds__(256) void mfma_gemm2_kernel(
    const bf16* __restrict__ A0, const bf16* __restrict__ A1,
    const bf16* __restrict__ Bt0, const bf16* __restrict__ Bt1,
    const float* __restrict__ bias0, const float* __restrict__ bias1,
    bf16* __restrict__ out0, bf16* __restrict__ out1,
    int M, int Nb, int do_relu) {
    const int lid = blockIdx.x;
    const int r8 = lid & 7, cc = (lid >> 3) & 1, g = lid >> 4;
    const int row_blk = g * 8 + r8;
    if (row_blk * 128 >= M) return;
    const bf16* A = blockIdx.y ? A1 : A0;
    const bf16* Bt = blockIdx.y ? Bt1 : Bt0;
    const float* bias = blockIdx.y ? bias1 : bias0;
    bf16* out = blockIdx.y ? out1 : out0;

    __shared__ bf16 smem[16384];
    bf16* As = smem;
    bf16* Bs = smem + 8192;

    const int t    = threadIdx.x;
    const int lane = t & 63;
    const int w    = t >> 6;
    const int row0 = row_blk * 128;
    const int col0 = cc * 128;

    f32x4 acc[4][4] = {};
    const int wm = (w >> 1) * 64, wn = (w & 1) * 64;
    const int fm = lane & 15, fC = lane >> 4;

    for (int k0 = 0; k0 < 256; k0 += 32) {
#pragma unroll
        for (int r = 0; r < 2; r++) {
            int flat = r * 256 + t;
            int fr = flat >> 2, fc = flat & 3;
            int fcg = fc ^ ((fr >> 1) & 3);          // swizzle
            int arow = row0 + fr;
            if (arow > M - 1) arow = M - 1;
            gl_lds16(&A[(size_t)arow * 256 + k0 + fcg * 8], &As[flat * 8]);
        }
#pragma unroll
        for (int r = 0; r < 2; r++) {
            int flat = r * 256 + t;
            int fr = flat >> 2, fc = flat & 3;
            int fcg = fc ^ ((fr >> 1) & 3);
            int brow = col0 + fr;                    // Bt padded to 256 rows
            gl_lds16(&Bt[(size_t)brow * 256 + k0 + fcg * 8], &Bs[flat * 8]);
        }
        __syncthreads();

        bf16x8 af[4], bfr[4];
#pragma unroll
        for (int i = 0; i < 4; i++) af[i] = frag_ld(As, wm + i * 16 + fm, fC);
#pragma unroll
        for (int i = 0; i < 4; i++) bfr[i] = frag_ld(Bs, wn + i * 16 + fm, fC);
#pragma unroll
        for (int i = 0; i < 4; i++)
#pragma unroll
            for (int j = 0; j < 4; j++)
                acc[i][j] = __builtin_amdgcn_mfma_f32_16x16x32_bf16(af[i], bfr[j], acc[i][j], 0, 0, 0);
        __syncthreads();
    }

    float bv[4];
#pragma unroll
    for (int j = 0; j < 4; j++) {
        int col = col0 + wn + fm + j * 16;
        bv[j] = (col < Nb) ? bias[col] : 0.f;
    }

#pragma unroll
    for (int p = 0; p < 2; p++) {
        if ((w >> 1) == p) {
#pragma unroll
            for (int i = 0; i < 4; i++)
#pragma unroll
                for (int j = 0; j < 4; j++)
#pragma unroll
                    for (int r2 = 0; r2 < 4; r2++) {
                        int rl = i * 16 + (lane >> 4) * 4 + r2;   // 0..63
                        int cl = wn + fm + j * 16;                // 0..127
                        float v = acc[i][j][r2] + bv[j];
                        if (do_relu) v = fmaxf(v, 0.f);
                        smem[rl * EPI_STRIDE + cl] = (bf16)v;
                    }
        }
        __syncthreads();
#pragma unroll
        for (int q = 0; q < 4; q++) {
            int flat = q * 256 + t;
            int rl = flat >> 4, seg = flat & 15;
            int grow = row0 + p * 64 + rl;
            if (grow < M)
                *(bf16x8*)&out[(size_t)grow * 256 + col0 + seg * 8] =
                    *(const bf16x8*)&smem[rl * EPI_STRIDE + seg * 8];
        }
        __syncthreads();
    }
}

// Fused W+Wr GEMM, both branches. Bt2 is 512x256: cols 0-255 -> out_lo (no act),
// 256-511 -> out_hi = relu(.+bias_hi). 4 col-blocks. grid (49*32, 2).
__global__ __launch_bounds__(256) void mfma_gemm_fused2_kernel(
    const bf16* __restrict__ A0, const bf16* __restrict__ A1,
    const bf16* __restrict__ Bt2_0, const bf16* __restrict__ Bt2_1,
    const float* __restrict__ bh0, const float* __restrict__ bh1,
    bf16* __restrict__ lo0, bf16* __restrict__ lo1,
    bf16* __restrict__ hi0, bf16* __restrict__ hi1, int M) {
    const int lid = blockIdx.x;
    const int r8 = lid & 7, cc = (lid >> 3) & 3, g = lid >> 5;
    const int row_blk = g * 8 + r8;
    if (row_blk * 128 >= M) return;
    const bf16* A = blockIdx.y ? A1 : A0;
    const bf16* Bt2 = blockIdx.y ? Bt2_1 : Bt2_0;
    const float* bias_hi = blockIdx.y ? bh1 : bh0;
    bf16* out_lo = blockIdx.y ? lo1 : lo0;
    bf16* out_hi = blockIdx.y ? hi1 : hi0;

    __shared__ bf16 smem[16384];
    bf16* As = smem;
    bf16* Bs = smem + 8192;

    const int t    = threadIdx.x;
    const int lane = t & 63;
    const int w    = t >> 6;
    const int row0 = row_blk * 128;
    const int col0 = cc * 128;   // 0..384

    f32x4 acc[4][4] = {};
    const int wm = (w >> 1) * 64, wn = (w & 1) * 64;
    const int fm = lane & 15, fC = lane >> 4;

    for (int k0 = 0; k0 < 256; k0 += 32) {
#pragma unroll
        for (int r = 0; r < 2; r++) {
            int flat = r * 256 + t;
            int fr = flat >> 2, fc = flat & 3;
            int fcg = fc ^ ((fr >> 1) & 3);
            int arow = row0 + fr;
            if (arow > M - 1) arow = M - 1;
            gl_lds16(&A[(size_t)arow * 256 + k0 + fcg * 8], &As[flat * 8]);
        }
#pragma unroll
        for (int r = 0; r < 2; r++) {
            int flat = r * 256 + t;
            int fr = flat >> 2, fc = flat & 3;
            int fcg = fc ^ ((fr >> 1) & 3);
            int brow = col0 + fr;
            gl_lds16(&Bt2[(size_t)brow * 256 + k0 + fcg * 8], &Bs[flat * 8]);
        }
        __syncthreads();

        bf16x8 af[4], bfr[4];
#pragma unroll
        for (int i = 0; i < 4; i++) af[i] = frag_ld(As, wm + i * 16 + fm, fC);
#pragma unroll
        for (int i = 0; i < 4; i++) bfr[i] = frag_ld(Bs, wn + i * 16 + fm, fC);
#pragma unroll
        for (int i = 0; i < 4; i++)
#pragma unroll
            for (int j = 0; j < 4; j++)
                acc[i][j] = __builtin_amdgcn_mfma_f32_16x16x32_bf16(af[i], bfr[j], acc[i][j], 0, 0, 0);
        __syncthreads();
    }

    const bool hi = (col0 >= 256);          // block-uniform
    bf16* out = hi ? out_hi : out_lo;
    const int cb = hi ? col0 - 256 : col0;

    float bv[4];
#pragma unroll
    for (int j = 0; j < 4; j++) {
        int col = cb + wn + fm + j * 16;
        bv[j] = hi ? bias_hi[col] : 0.f;
    }

#pragma unroll
    for (int p = 0; p < 2; p++) {
        if ((w >> 1) == p) {
#pragma unroll
            for (int i = 0; i < 4; i++)
#pragma unroll
                for (int j = 0; j < 4; j++)
#pragma unroll
                    for (int r2 = 0; r2 < 4; r2++) {
                        int rl = i * 16 + (lane >> 4) * 4 + r2;
                        int cl = wn + fm + j * 16;
                        float v = acc[i][j][r2] + bv[j];
                        if (hi) v = fmaxf(v, 0.f);
                        smem[rl * EPI_STRIDE + cl] = (bf16)v;
                    }
        }
        __syncthreads();
#pragma unroll
        for (int q = 0; q < 4; q++) {
            int flat = q * 256 + t;
            int rl = flat >> 4, seg = flat & 15;
            int grow = row0 + p * 64 + rl;
            if (grow < M)
                *(bf16x8*)&out[(size_t)grow * 256 + cb + seg * 8] =
                    *(const bf16x8*)&smem[rl * EPI_STRIDE + seg * 8];
        }
        __syncthreads();
    }
}

// ---------------------------------------------------------------------------
// edge aggregation + combine, both branches (blockIdx.y):
// H[v] = relu(sum_{e: dst=v} hW[src[e]] + b) + res[v]
// one wave per dst node; lane covers 8 feats (16B), half-waves cover edges.
// Index preload (1 coalesced read of up to 64 idx) + branch-free predicated
// 16-edge window -> 8 gathers in flight per half-wave, no address-dep stall.
// ---------------------------------------------------------------------------
__global__ __launch_bounds__(256) void agg_combine2_kernel(
    const bf16* __restrict__ hW0, const bf16* __restrict__ hW1,
    const int* __restrict__ csr0, const int* __restrict__ csr1,
    const int* __restrict__ offs0, const int* __restrict__ offs1,
    const float* __restrict__ bias0, const float* __restrict__ bias1,
    const bf16* __restrict__ res0, const bf16* __restrict__ res1,
    bf16* __restrict__ H0, bf16* __restrict__ H1, int n_nodes) {
    const bf16* hW = blockIdx.y ? hW1 : hW0;
    const int* csr_src = blockIdx.y ? csr1 : csr0;
    const int* offsets = blockIdx.y ? offs1 : offs0;
    const float* bias = blockIdx.y ? bias1 : bias0;
    const bf16* res = blockIdx.y ? res1 : res0;
    bf16* H = blockIdx.y ? H1 : H0;

    int wave = threadIdx.x >> 6;
    int lane = threadIdx.x & 63;
    int node = blockIdx.x * 4 + wave;
    if (node >= n_nodes) return;
    int beg = offsets[node], end = offsets[node + 1];
    int deg = end - beg;
    const int half = lane >> 5;
    const int fo   = (lane & 31) * 8;

    // preload first 64 edge indices, one per lane (single coalesced read)
    int myidx = (beg + lane < end) ? csr_src[beg + lane] : 0;
    // prefetch residual row early (independent of the gather stream)
    bf16x8 rv = *(const bf16x8*)&res[(size_t)node * DD + fo];

    float acc[8] = {};
    const int lim = deg < 64 ? deg : 64;
    for (int j0 = 0; j0 < lim; j0 += 16) {
        float wgt[8];
        bf16x8 v[8];
#pragma unroll
        for (int q = 0; q < 8; q++) {
            int e = j0 + 2 * q + half;
            bool go = e < lim;
            int s = __shfl(myidx, go ? e : 0, 64);  // clamp -> L1-hit duplicate of edge 0
            v[q] = *(const bf16x8*)&hW[(size_t)s * DD + fo];
            wgt[q] = go ? 1.f : 0.f;
        }
#pragma unroll
        for (int q = 0; q < 8; q++)
#pragma unroll
            for (int r = 0; r < 8; r++) acc[r] = fmaf(wgt[q], (float)v[q][r], acc[r]);
    }
    // rare overflow: degree > 64 (direct pairwise reads)
    for (int j = 64; j + half < deg; j += 2) {
        int s = csr_src[beg + j + half];
        bf16x8 v = *(const bf16x8*)&hW[(size_t)s * DD + fo];
#pragma unroll
        for (int r = 0; r < 8; r++) acc[r] += (float)v[r];
    }
#pragma unroll
    for (int q = 0; q < 8; q++) acc[q] += __shfl_xor(acc[q], 32, 64);

    if (half == 0) {
        float4 b0 = *(const float4*)&bias[fo];
        float4 b1 = *(const float4*)&bias[fo + 4];
        bf16x8 o;
        o[0] = (bf16)(fmaxf(acc[0] + b0.x, 0.f) + (float)rv[0]);
        o[1] = (bf16)(fmaxf(acc[1] + b0.y, 0.f) + (float)rv[1]);
        o[2] = (bf16)(fmaxf(acc[2] + b0.z, 0.f) + (float)rv[2]);
        o[3] = (bf16)(fmaxf(acc[3] + b0.w, 0.f) + (float)rv[3]);
        o[4] = (bf16)(fmaxf(acc[4] + b1.x, 0.f) + (float)rv[4]);
        o[5] = (bf16)(fmaxf(acc[5] + b1.y, 0.f) + (float)rv[5]);
        o[6] = (bf16)(fmaxf(acc[6] + b1.z, 0.f) + (float)rv[6]);
        o[7] = (bf16)(fmaxf(acc[7] + b1.w, 0.f) + (float)rv[7]);
        *(bf16x8*)&H[(size_t)node * DD + fo] = o;
    }
}

// ---------------------------------------------------------------------------
// per-graph segment sum of P[N_nodes, 256(stride)] bf16, cols<GFEAT; both branches
// ---------------------------------------------------------------------------
__global__ __launch_bounds__(256) void graph_reduce2_kernel(
    const bf16* __restrict__ P0, const bf16* __restrict__ P1,
    const int* __restrict__ g0, const int* __restrict__ g1,
    float* __restrict__ G0, float* __restrict__ G1, int n_nodes) {
    const bf16* P = blockIdx.y ? P1 : P0;
    const int* gids = blockIdx.y ? g1 : g0;
    float* G = blockIdx.y ? G1 : G0;

    int g = blockIdx.x;
    int lo = 0, hi = n_nodes;
    while (lo < hi) { int mid = (lo + hi) >> 1; if (gids[mid] < g) lo = mid + 1; else hi = mid; }
    int beg = lo;
    hi = n_nodes;
    while (lo < hi) { int mid = (lo + hi) >> 1; if (gids[mid] < g + 1) lo = mid + 1; else hi = mid; }
    int end = lo;

    int c = threadIdx.x;
    if (c < GFEAT) {
        float acc = 0.f;
        for (int r = beg; r < end; r++) acc += (float)P[(size_t)r * 256 + c];
        G[(size_t)g * GFEAT + c] = acc;
    }
}

__global__ __launch_bounds__(256) void predictor_kernel(const float* __restrict__ G1,
                                                        const float* __restrict__ G2,
                                                        const float* __restrict__ Wp,
                                                        const float* __restrict__ bp,
                                                        float* __restrict__ out) {
    int i = blockIdx.x * 256 + threadIdx.x;
    if (i >= NG) return;
    float acc = bp[0];
    for (int f = 0; f < GFEAT; f++)
        acc += (G1[i * GFEAT + f] + G2[i * GFEAT + f]) * Wp[f];
    out[i] = acc;
}

extern "C" void kernel_launch(void* const* d_in, const int* in_sizes, int n_in,
                              void* d_out, int out_size, void* d_ws, size_t ws_size,
                              hipStream_t stream) {
    const float* X1   = (const float*)d_in[0];
    const float* X2   = (const float*)d_in[2];
    const int*   src1 = (const int*)d_in[4];
    const int*   dst1 = (const int*)d_in[5];
    const int*   gid1 = (const int*)d_in[6];
    const int*   src2 = (const int*)d_in[7];
    const int*   dst2 = (const int*)d_in[8];
    const int*   gid2 = (const int*)d_in[9];
    const float* W1  = (const float*)d_in[10]; const float* b1  = (const float*)d_in[11];
    const float* Wr1 = (const float*)d_in[12]; const float* br1 = (const float*)d_in[13];
    const float* W2  = (const float*)d_in[14]; const float* b2  = (const float*)d_in[15];
    const float* Wr2 = (const float*)d_in[16]; const float* br2 = (const float*)d_in[17];
    const float* Ri1 = (const float*)d_in[18]; const float* rbi1 = (const float*)d_in[19];
    const float* Ro1 = (const float*)d_in[20]; const float* rbo1 = (const float*)d_in[21];
    const float* Ri2 = (const float*)d_in[22]; const float* rbi2 = (const float*)d_in[23];
    const float* Ro2 = (const float*)d_in[24]; const float* rbo2 = (const float*)d_in[25];
    const float* Wp  = (const float*)d_in[26]; const float* bp  = (const float*)d_in[27];

    // workspace layout (per-branch buffers; lifetime-disjoint aliases)
    const size_t NB = (size_t)NN * DD * sizeof(bf16);   // 25.6 MB
    char* p = (char*)d_ws;
    bf16* XbH1 = (bf16*)p; p += NB;     // Xb1 (conv->fused), then H1 (agg->Ri)
    bf16* XbH2 = (bf16*)p; p += NB;
    bf16* hWR1 = (bf16*)p; p += NB;     // eb1 (CSR), then hW1 (fused->agg), then R1 (Ri->Ro)
    bf16* hWR2 = (bf16*)p; p += NB;
    bf16* resP1 = (bf16*)p; p += NB;    // res1 (fused->agg), then P1 (Ro->reduce)
    bf16* resP2 = (bf16*)p; p += NB;
    float* G1  = (float*)p; p += (size_t)NG * GFEAT * sizeof(float);
    float* G2  = (float*)p; p += (size_t)NG * GFEAT * sizeof(float);
    // 8 weight mats; order: W1,Wr1,Ri1,Ro1,W2,Wr2,Ri2,Ro2 (W|Wr contiguous = fused Bt)
    bf16* Wbase = (bf16*)p; p += 8 * 65536 * sizeof(bf16);
    int* offs1 = (int*)p; p += (NN + 1) * sizeof(int);
    int* offs2 = (int*)p; p += (NN + 1) * sizeof(int);
    int* cnt1  = (int*)p; p += NBKT * NCHUNK * sizeof(int);
    int* cnt2  = (int*)p; p += NBKT * NCHUNK * sizeof(int);
    int* csr1  = (int*)p; p += NE * sizeof(int);
    int* csr2  = (int*)p; p += NE * sizeof(int);
    int2* eb1 = (int2*)hWR1;   // live only during CSR build (before fused writes hW)
    int2* eb2 = (int2*)hWR2;

    conv_w8_kernel<<<dim3(256, 8), 256, 0, stream>>>(W1, Wr1, Ri1, Ro1, W2, Wr2, Ri2, Ro2, Wbase);
    conv_x2_kernel<<<dim3((NN * DD / 4 + 255) / 256, 2), 256, 0, stream>>>(
        X1, X2, XbH1, XbH2, NN * DD / 4);

    // CSR build (both branches): two-level counting sort, no global atomics
    csr_coarse_hist_kernel<<<dim3(NCHUNK, 2), 256, 0, stream>>>(dst1, dst2, cnt1, cnt2);
    csr_scan_kernel<<<dim3(1, 2), 1024, 0, stream>>>(cnt1, cnt2, offs1, offs2);
    csr_partition_kernel<<<dim3(NCHUNK, 2), 256, 0, stream>>>(
        src1, src2, dst1, dst2, cnt1, cnt2, eb1, eb2);
    csr_bucket_sort_kernel<<<dim3(NBKT, 2), 512, 0, stream>>>(
        cnt1, cnt2, eb1, eb2, offs1, offs2, csr1, csr2);

    // hW = X @ W ; res = relu(X @ Wr + br)          [both branches]
    mfma_gemm_fused2_kernel<<<dim3(49 * 32, 2), 256, 0, stream>>>(
        XbH1, XbH2, Wbase + 0 * 65536, Wbase + 4 * 65536, br1, br2,
        hWR1, hWR2, resP1, resP2, NN);
    // H = relu(agg + b) + res                       [both branches]
    agg_combine2_kernel<<<dim3((NN + 3) / 4, 2), 256, 0, stream>>>(
        hWR1, hWR2, csr1, csr2, offs1, offs2, b1, b2, resP1, resP2, XbH1, XbH2, NN);
    // R = relu(H @ Ri + rbi)                        [both branches]
    mfma_gemm2_kernel<<<dim3(49 * 16, 2), 256, 0, stream>>>(
        XbH1, XbH2, Wbase + 2 * 65536, Wbase + 6 * 65536, rbi1, rbi2,
        hWR1, hWR2, NN, DD, 1);
    // P = R @ Ro + rbo (bf16, stride 256, cols<200) [both branches]
    mfma_gemm2_kernel<<<dim3(49 * 16, 2), 256, 0, stream>>>(
        hWR1, hWR2, Wbase + 3 * 65536, Wbase + 7 * 65536, rbo1, rbo2,
        resP1, resP2, NN, GFEAT, 0);
    // G = segment_sum(P, gids)                      [both branches]
    graph_reduce2_kernel<<<dim3(NG, 2), 256, 0, stream>>>(
        resP1, resP2, gid1, gid2, G1, G2, NN);

    predictor_kernel<<<(NG + 255) / 256, 256, 0, stream>>>(G1, G2, Wp, bp, (float*)d_out);
}

// Round 5
// 557.434 us; speedup vs baseline: 1.8819x; 1.0272x over previous
//
#include <hip/hip_runtime.h>

// Problem constants (fixed by reference)
#define NN 50000      // nodes
#define NE 800000     // edges
#define DD 256        // node feat dim
#define GFEAT 200     // graph feat dim
#define NG 512        // graphs

typedef __bf16 bf16;
typedef bf16 bf16x4 __attribute__((ext_vector_type(4)));
typedef bf16 bf16x8 __attribute__((ext_vector_type(8)));
typedef float f32x4 __attribute__((ext_vector_type(4)));

// async global->LDS, 16B per lane. HW dest = wave-uniform base + lane*16.
__device__ __forceinline__ void gl_lds16(const bf16* g, bf16* l) {
    __builtin_amdgcn_global_load_lds(
        (const __attribute__((address_space(1))) uint32_t*)(g),
        (__attribute__((address_space(3))) uint32_t*)(l), 16, 0, 0);
}

// BK=64 LDS tile [128][64]; 16B chunk c holds global chunk c^((row>>1)&7)
__device__ __forceinline__ bf16x8 frag_ld64(const bf16* s, int R, int C) {
    return *(const bf16x8*)&s[R * 64 + ((C ^ ((R >> 1) & 7)) << 3)];
}

#define EPI_STRIDE 136   // bf16 elems; 272 B row stride (16B-aligned, bank-shift 4/row)

// ---------------------------------------------------------------------------
// conversions
// ---------------------------------------------------------------------------
__global__ __launch_bounds__(256) void conv_x2_kernel(const float* __restrict__ in0,
                                                      const float* __restrict__ in1,
                                                      bf16* __restrict__ out0,
                                                      bf16* __restrict__ out1, int n4) {
    const float* in = blockIdx.y ? in1 : in0;
    bf16* out = blockIdx.y ? out1 : out0;
    int i = blockIdx.x * 256 + threadIdx.x;
    if (i < n4) {
        float4 v = ((const float4*)in)[i];
        bf16x4 o;
        o[0] = (bf16)v.x; o[1] = (bf16)v.y; o[2] = (bf16)v.z; o[3] = (bf16)v.w;
        ((bf16x4*)out)[i] = o;
    }
}

// 8 weight matrices fp32 [K][N] -> bf16 [256][256] = [n][k] transposed, zero-padded.
__global__ __launch_bounds__(256) void conv_w8_kernel(
    const float* __restrict__ w0, const float* __restrict__ w1,
    const float* __restrict__ w2, const float* __restrict__ w3,
    const float* __restrict__ w4, const float* __restrict__ w5,
    const float* __restrict__ w6, const float* __restrict__ w7,
    bf16* __restrict__ out_base) {
    const float* ws[8] = {w0, w1, w2, w3, w4, w5, w6, w7};
    const int Ns[8] = {DD, DD, DD, GFEAT, DD, DD, DD, GFEAT};
    int m = blockIdx.y;
    const float* in = ws[m];
    int N = Ns[m];
    int idx = blockIdx.x * 256 + threadIdx.x;   // 0..65535 over [n][k]
    int n = idx >> 8, k = idx & 255;
    float v = (n < N) ? in[k * N + n] : 0.f;
    out_base[(size_t)m * 65536 + idx] = (bf16)v;
}

__global__ __launch_bounds__(256) void zero_g_kernel(float* __restrict__ G0,
                                                     float* __restrict__ G1) {
    float* G = blockIdx.y ? G1 : G0;
    int i = blockIdx.x * 256 + threadIdx.x;
    if (i < NG * GFEAT) G[i] = 0.f;
}

// ---------------------------------------------------------------------------
// CSR build: two-level counting sort, zero global atomics, O(1) reads/edge.
// ---------------------------------------------------------------------------
#define NBKT   128
#define NPB    391            // ceil(NN / NBKT); 128*391 = 50048
#define NCHUNK 256
#define CE     ((NE + NCHUNK - 1) / NCHUNK)   // 3125 edges per chunk

__global__ __launch_bounds__(256) void csr_coarse_hist_kernel(
    const int* __restrict__ d0, const int* __restrict__ d1,
    int* __restrict__ cnt0, int* __restrict__ cnt1) {
    const int blk = blockIdx.x, t = threadIdx.x;
    const int* dst = blockIdx.y ? d1 : d0;
    int* cnt = blockIdx.y ? cnt1 : cnt0;
    __shared__ int hist[NBKT];
    if (t < NBKT) hist[t] = 0;
    __syncthreads();
    const int e0 = blk * CE;
    const int e1 = (e0 + CE < NE) ? e0 + CE : NE;
    for (int e = e0 + t; e < e1; e += 256)
        atomicAdd(&hist[dst[e] / NPB], 1);
    __syncthreads();
    if (t < NBKT) cnt[t * NCHUNK + blk] = hist[t];   // bucket-major
}

__global__ __launch_bounds__(1024) void csr_scan_kernel(
    int* __restrict__ cnt0, int* __restrict__ cnt1,
    int* __restrict__ offs0, int* __restrict__ offs1) {
    int* cnt = blockIdx.y ? cnt1 : cnt0;
    const int t = threadIdx.x;
    const int PER = (NBKT * NCHUNK) / 1024;   // 32
    int v[PER];
    int sum = 0;
    const int base = t * PER;
#pragma unroll
    for (int i = 0; i < PER; i += 4) {
        int4 q = *(const int4*)&cnt[base + i];
        v[i] = q.x; v[i + 1] = q.y; v[i + 2] = q.z; v[i + 3] = q.w;
        sum += q.x + q.y + q.z + q.w;
    }
    __shared__ int s[1024];
    s[t] = sum;
    __syncthreads();
    for (int off = 1; off < 1024; off <<= 1) {
        int a = (t >= off) ? s[t - off] : 0;
        __syncthreads();
        s[t] += a;
        __syncthreads();
    }
    int run = s[t] - sum;   // exclusive prefix of this thread's chunk
#pragma unroll
    for (int i = 0; i < PER; i++) { int c = v[i]; cnt[base + i] = run; run += c; }
    if (t == 0) (blockIdx.y ? offs1 : offs0)[NN] = NE;
}

__global__ __launch_bounds__(256) void csr_partition_kernel(
    const int* __restrict__ sA, const int* __restrict__ sB,
    const int* __restrict__ d0, const int* __restrict__ d1,
    const int* __restrict__ cnt0, const int* __restrict__ cnt1,
    int2* __restrict__ eb0, int2* __restrict__ eb1) {
    const int blk = blockIdx.x, t = threadIdx.x;
    const int* src = blockIdx.y ? sB : sA;
    const int* dst = blockIdx.y ? d1 : d0;
    const int* cnt = blockIdx.y ? cnt1 : cnt0;
    int2* eb = blockIdx.y ? eb1 : eb0;
    __shared__ int cur[NBKT];
    if (t < NBKT) cur[t] = cnt[t * NCHUNK + blk];   // this chunk's start in each bucket
    __syncthreads();
    const int e0 = blk * CE;
    const int e1 = (e0 + CE < NE) ? e0 + CE : NE;
    for (int e = e0 + t; e < e1; e += 256) {
        int d = dst[e], s = src[e];
        int pos = atomicAdd(&cur[d / NPB], 1);      // LDS atomic, range disjoint per block
        eb[pos] = make_int2(s, d);
    }
}

__global__ __launch_bounds__(512) void csr_bucket_sort_kernel(
    const int* __restrict__ cnt0, const int* __restrict__ cnt1,
    const int2* __restrict__ eb0, const int2* __restrict__ eb1,
    int* __restrict__ offs0, int* __restrict__ offs1,
    int* __restrict__ csr0, int* __restrict__ csr1) {
    const int b = blockIdx.x, t = threadIdx.x;
    const int* cnt = blockIdx.y ? cnt1 : cnt0;
    const int2* eb = blockIdx.y ? eb1 : eb0;
    int* offs = blockIdx.y ? offs1 : offs0;
    int* csr = blockIdx.y ? csr1 : csr0;
    const int lo = b * NPB;
    const int ncnt = (NN - lo < NPB) ? (NN - lo) : NPB;
    const int beg = cnt[b * NCHUNK];
    const int end = (b == NBKT - 1) ? NE : cnt[(b + 1) * NCHUNK];

    __shared__ int hist[NPB];
    __shared__ int s[512];
    if (t < NPB) hist[t] = 0;
    __syncthreads();
    for (int i = beg + t; i < end; i += 512)
        atomicAdd(&hist[eb[i].y - lo], 1);
    __syncthreads();

    int h = (t < NPB) ? hist[t] : 0;
    s[t] = h;
    __syncthreads();
    for (int off = 1; off < 512; off <<= 1) {
        int a = (t >= off) ? s[t - off] : 0;
        __syncthreads();
        s[t] += a;
        __syncthreads();
    }
    int excl = s[t] - h;
    __syncthreads();
    if (t < NPB) hist[t] = excl;                 // local cursors
    if (t < ncnt) offs[lo + t] = beg + excl;     // final global offsets
    __syncthreads();

    for (int i = beg + t; i < end; i += 512) {
        int2 v = eb[i];
        int pos = atomicAdd(&hist[v.y - lo], 1);
        csr[beg + pos] = v.x;                    // contiguous ~25 KB region per block
    }
}

// ---------------------------------------------------------------------------
// BK=64 staging for a 128x64 bf16 tile (16 KB): 4 x gl_lds16 per thread.
// flat in [0,1024): row = flat>>3 (0..127), chunk = flat&7, swizzled source.
// ---------------------------------------------------------------------------
#define STAGE64(MAT, base_row, CLAMP_M)                                          \
    _Pragma("unroll")                                                            \
    for (int r_ = 0; r_ < 4; r_++) {                                             \
        int flat_ = r_ * 256 + t;                                                \
        int fr_ = flat_ >> 3, fc_ = flat_ & 7;                                   \
        int fcg_ = fc_ ^ ((fr_ >> 1) & 7);                                       \
        int row_ = (base_row) + fr_;                                             \
        if (CLAMP_M && row_ > M - 1) row_ = M - 1;                               \
        gl_lds16(&MAT[(size_t)row_ * 256 + k0 + fcg_ * 8],                       \
                 &(((r_ < 2) ? As : As) )[0] + 0);                               \
    }

// (macro above unused; loops written inline for clarity)

// ---------------------------------------------------------------------------
// bf16 MFMA GEMM, BOTH BRANCHES (blockIdx.y), K=256, BK=64, out width 256.
// XCD-swizzled block decode. Generic: 2 col-blocks. grid (49*16, 2).
// ---------------------------------------------------------------------------
__global__ __launch_bounds__(256) void mfma_gemm2_kernel(
    const bf16* __restrict__ A0, const bf16* __restrict__ A1,
    const bf16* __restrict__ Bt0, const bf16* __restrict__ Bt1,
    const float* __restrict__ bias0, const float* __restrict__ bias1,
    bf16* __restrict__ out0, bf16* __restrict__ out1,
    int M, int Nb, int do_relu) {
    const int lid = blockIdx.x;
    const int r8 = lid & 7, cc = (lid >> 3) & 1, g = lid >> 4;
    const int row_blk = g * 8 + r8;
    if (row_blk * 128 >= M) return;
    const bf16* A = blockIdx.y ? A1 : A0;
    const bf16* Bt = blockIdx.y ? Bt1 : Bt0;
    const float* bias = blockIdx.y ? bias1 : bias0;
    bf16* out = blockIdx.y ? out1 : out0;

    __shared__ bf16 smem[16384];     // As(16KB) | Bs(16KB); epilogue reuses
    bf16* As = smem;
    bf16* Bs = smem + 8192;

    const int t    = threadIdx.x;
    const int lane = t & 63;
    const int w    = t >> 6;
    const int row0 = row_blk * 128;
    const int col0 = cc * 128;

    f32x4 acc[4][4] = {};
    const int wm = (w >> 1) * 64, wn = (w & 1) * 64;
    const int fm = lane & 15, fC = lane >> 4;

    for (int k0 = 0; k0 < 256; k0 += 64) {
#pragma unroll
        for (int r = 0; r < 4; r++) {
            int flat = r * 256 + t;
            int fr = flat >> 3, fc = flat & 7;
            int fcg = fc ^ ((fr >> 1) & 7);
            int arow = row0 + fr;
            if (arow > M - 1) arow = M - 1;
            gl_lds16(&A[(size_t)arow * 256 + k0 + fcg * 8], &As[flat * 8]);
        }
#pragma unroll
        for (int r = 0; r < 4; r++) {
            int flat = r * 256 + t;
            int fr = flat >> 3, fc = flat & 7;
            int fcg = fc ^ ((fr >> 1) & 7);
            int brow = col0 + fr;                    // Bt padded to 256 rows
            gl_lds16(&Bt[(size_t)brow * 256 + k0 + fcg * 8], &Bs[flat * 8]);
        }
        __syncthreads();
#pragma unroll
        for (int s = 0; s < 2; s++) {
            bf16x8 af[4], bfr[4];
#pragma unroll
            for (int i = 0; i < 4; i++) af[i] = frag_ld64(As, wm + i * 16 + fm, s * 4 + fC);
#pragma unroll
            for (int i = 0; i < 4; i++) bfr[i] = frag_ld64(Bs, wn + i * 16 + fm, s * 4 + fC);
#pragma unroll
            for (int i = 0; i < 4; i++)
#pragma unroll
                for (int j = 0; j < 4; j++)
                    acc[i][j] = __builtin_amdgcn_mfma_f32_16x16x32_bf16(af[i], bfr[j], acc[i][j], 0, 0, 0);
        }
        __syncthreads();
    }

    float bv[4];
#pragma unroll
    for (int j = 0; j < 4; j++) {
        int col = col0 + wn + fm + j * 16;
        bv[j] = (col < Nb) ? bias[col] : 0.f;
    }

#pragma unroll
    for (int p = 0; p < 2; p++) {
        if ((w >> 1) == p) {
#pragma unroll
            for (int i = 0; i < 4; i++)
#pragma unroll
                for (int j = 0; j < 4; j++)
#pragma unroll
                    for (int r2 = 0; r2 < 4; r2++) {
                        int rl = i * 16 + (lane >> 4) * 4 + r2;   // 0..63
                        int cl = wn + fm + j * 16;                // 0..127
                        float v = acc[i][j][r2] + bv[j];
                        if (do_relu) v = fmaxf(v, 0.f);
                        smem[rl * EPI_STRIDE + cl] = (bf16)v;
                    }
        }
        __syncthreads();
#pragma unroll
        for (int q = 0; q < 4; q++) {
            int flat = q * 256 + t;
            int rl = flat >> 4, seg = flat & 15;
            int grow = row0 + p * 64 + rl;
            if (grow < M)
                *(bf16x8*)&out[(size_t)grow * 256 + col0 + seg * 8] =
                    *(const bf16x8*)&smem[rl * EPI_STRIDE + seg * 8];
        }
        __syncthreads();
    }
}

// Fused W+Wr GEMM, both branches, BK=64. Bt2 is 512x256: cols 0-255 -> out_lo
// (no act), 256-511 -> out_hi = relu(.+bias_hi). 4 col-blocks. grid (49*32, 2).
__global__ __launch_bounds__(256) void mfma_gemm_fused2_kernel(
    const bf16* __restrict__ A0, const bf16* __restrict__ A1,
    const bf16* __restrict__ Bt2_0, const bf16* __restrict__ Bt2_1,
    const float* __restrict__ bh0, const float* __restrict__ bh1,
    bf16* __restrict__ lo0, bf16* __restrict__ lo1,
    bf16* __restrict__ hi0, bf16* __restrict__ hi1, int M) {
    const int lid = blockIdx.x;
    const int r8 = lid & 7, cc = (lid >> 3) & 3, g = lid >> 5;
    const int row_blk = g * 8 + r8;
    if (row_blk * 128 >= M) return;
    const bf16* A = blockIdx.y ? A1 : A0;
    const bf16* Bt2 = blockIdx.y ? Bt2_1 : Bt2_0;
    const float* bias_hi = blockIdx.y ? bh1 : bh0;
    bf16* out_lo = blockIdx.y ? lo1 : lo0;
    bf16* out_hi = blockIdx.y ? hi1 : hi0;

    __shared__ bf16 smem[16384];
    bf16* As = smem;
    bf16* Bs = smem + 8192;

    const int t    = threadIdx.x;
    const int lane = t & 63;
    const int w    = t >> 6;
    const int row0 = row_blk * 128;
    const int col0 = cc * 128;   // 0..384

    f32x4 acc[4][4] = {};
    const int wm = (w >> 1) * 64, wn = (w & 1) * 64;
    const int fm = lane & 15, fC = lane >> 4;

    for (int k0 = 0; k0 < 256; k0 += 64) {
#pragma unroll
        for (int r = 0; r < 4; r++) {
            int flat = r * 256 + t;
            int fr = flat >> 3, fc = flat & 7;
            int fcg = fc ^ ((fr >> 1) & 7);
            int arow = row0 + fr;
            if (arow > M - 1) arow = M - 1;
            gl_lds16(&A[(size_t)arow * 256 + k0 + fcg * 8], &As[flat * 8]);
        }
#pragma unroll
        for (int r = 0; r < 4; r++) {
            int flat = r * 256 + t;
            int fr = flat >> 3, fc = flat & 7;
            int fcg = fc ^ ((fr >> 1) & 7);
            int brow = col0 + fr;
            gl_lds16(&Bt2[(size_t)brow * 256 + k0 + fcg * 8], &Bs[flat * 8]);
        }
        __syncthreads();
#pragma unroll
        for (int s = 0; s < 2; s++) {
            bf16x8 af[4], bfr[4];
#pragma unroll
            for (int i = 0; i < 4; i++) af[i] = frag_ld64(As, wm + i * 16 + fm, s * 4 + fC);
#pragma unroll
            for (int i = 0; i < 4; i++) bfr[i] = frag_ld64(Bs, wn + i * 16 + fm, s * 4 + fC);
#pragma unroll
            for (int i = 0; i < 4; i++)
#pragma unroll
                for (int j = 0; j < 4; j++)
                    acc[i][j] = __builtin_amdgcn_mfma_f32_16x16x32_bf16(af[i], bfr[j], acc[i][j], 0, 0, 0);
        }
        __syncthreads();
    }

    const bool hi = (col0 >= 256);          // block-uniform
    bf16* out = hi ? out_hi : out_lo;
    const int cb = hi ? col0 - 256 : col0;

    float bv[4];
#pragma unroll
    for (int j = 0; j < 4; j++) {
        int col = cb + wn + fm + j * 16;
        bv[j] = hi ? bias_hi[col] : 0.f;
    }

#pragma unroll
    for (int p = 0; p < 2; p++) {
        if ((w >> 1) == p) {
#pragma unroll
            for (int i = 0; i < 4; i++)
#pragma unroll
                for (int j = 0; j < 4; j++)
#pragma unroll
                    for (int r2 = 0; r2 < 4; r2++) {
                        int rl = i * 16 + (lane >> 4) * 4 + r2;
                        int cl = wn + fm + j * 16;
                        float v = acc[i][j][r2] + bv[j];
                        if (hi) v = fmaxf(v, 0.f);
                        smem[rl * EPI_STRIDE + cl] = (bf16)v;
                    }
        }
        __syncthreads();
#pragma unroll
        for (int q = 0; q < 4; q++) {
            int flat = q * 256 + t;
            int rl = flat >> 4, seg = flat & 15;
            int grow = row0 + p * 64 + rl;
            if (grow < M)
                *(bf16x8*)&out[(size_t)grow * 256 + cb + seg * 8] =
                    *(const bf16x8*)&smem[rl * EPI_STRIDE + seg * 8];
        }
        __syncthreads();
    }
}

// Ro GEMM + per-graph segment reduce fused, both branches, BK=64.
// P-tile (bias added, no relu) goes to LDS; per-column fp32 segment sums over
// sorted gids are atomicAdd'ed into G[graph][col]. No P buffer at all.
// grid (49*16, 2) like mfma_gemm2.
__global__ __launch_bounds__(256) void mfma_gemm_reduce2_kernel(
    const bf16* __restrict__ A0, const bf16* __restrict__ A1,
    const bf16* __restrict__ Bt0, const bf16* __restrict__ Bt1,
    const float* __restrict__ bias0, const float* __restrict__ bias1,
    const int* __restrict__ gid0, const int* __restrict__ gid1,
    float* __restrict__ G0, float* __restrict__ G1, int M, int Nb) {
    const int lid = blockIdx.x;
    const int r8 = lid & 7, cc = (lid >> 3) & 1, g = lid >> 4;
    const int row_blk = g * 8 + r8;
    if (row_blk * 128 >= M) return;
    const bf16* A = blockIdx.y ? A1 : A0;
    const bf16* Bt = blockIdx.y ? Bt1 : Bt0;
    const float* bias = blockIdx.y ? bias1 : bias0;
    const int* gids = blockIdx.y ? gid1 : gid0;
    float* G = blockIdx.y ? G1 : G0;

    __shared__ bf16 smem[16384];
    bf16* As = smem;
    bf16* Bs = smem + 8192;

    const int t    = threadIdx.x;
    const int lane = t & 63;
    const int w    = t >> 6;
    const int row0 = row_blk * 128;
    const int col0 = cc * 128;

    f32x4 acc[4][4] = {};
    const int wm = (w >> 1) * 64, wn = (w & 1) * 64;
    const int fm = lane & 15, fC = lane >> 4;

    for (int k0 = 0; k0 < 256; k0 += 64) {
#pragma unroll
        for (int r = 0; r < 4; r++) {
            int flat = r * 256 + t;
            int fr = flat >> 3, fc = flat & 7;
            int fcg = fc ^ ((fr >> 1) & 7);
            int arow = row0 + fr;
            if (arow > M - 1) arow = M - 1;
            gl_lds16(&A[(size_t)arow * 256 + k0 + fcg * 8], &As[flat * 8]);
        }
#pragma unroll
        for (int r = 0; r < 4; r++) {
            int flat = r * 256 + t;
            int fr = flat >> 3, fc = flat & 7;
            int fcg = fc ^ ((fr >> 1) & 7);
            int brow = col0 + fr;
            gl_lds16(&Bt[(size_t)brow * 256 + k0 + fcg * 8], &Bs[flat * 8]);
        }
        __syncthreads();
#pragma unroll
        for (int s = 0; s < 2; s++) {
            bf16x8 af[4], bfr[4];
#pragma unroll
            for (int i = 0; i < 4; i++) af[i] = frag_ld64(As, wm + i * 16 + fm, s * 4 + fC);
#pragma unroll
            for (int i = 0; i < 4; i++) bfr[i] = frag_ld64(Bs, wn + i * 16 + fm, s * 4 + fC);
#pragma unroll
            for (int i = 0; i < 4; i++)
#pragma unroll
                for (int j = 0; j < 4; j++)
                    acc[i][j] = __builtin_amdgcn_mfma_f32_16x16x32_bf16(af[i], bfr[j], acc[i][j], 0, 0, 0);
        }
        __syncthreads();
    }

    float bv[4];
#pragma unroll
    for (int j = 0; j < 4; j++) {
        int col = col0 + wn + fm + j * 16;
        bv[j] = (col < Nb) ? bias[col] : 0.f;
    }

#pragma unroll
    for (int p = 0; p < 2; p++) {
        if ((w >> 1) == p) {
#pragma unroll
            for (int i = 0; i < 4; i++)
#pragma unroll
                for (int j = 0; j < 4; j++)
#pragma unroll
                    for (int r2 = 0; r2 < 4; r2++) {
                        int rl = i * 16 + (lane >> 4) * 4 + r2;
                        int cl = wn + fm + j * 16;
                        smem[rl * EPI_STRIDE + cl] = (bf16)(acc[i][j][r2] + bv[j]);
                    }
        }
        __syncthreads();
        // segment reduce: 2 threads per column, 32 rows each; sorted gids ->
        // flush partial into G on boundary (fp32 atomic, device scope).
        {
            int c = t & 127, rh = t >> 7;
            int colg = col0 + c;
            if (colg < Nb) {
                float run = 0.f;
                int gprev = -1;
                for (int r = 0; r < 32; r++) {
                    int grow = row0 + p * 64 + rh * 32 + r;
                    if (grow >= M) break;
                    int gg = gids[grow];
                    if (gg != gprev) {
                        if (gprev >= 0) atomicAdd(&G[(size_t)gprev * GFEAT + colg], run);
                        run = 0.f;
                        gprev = gg;
                    }
                    run += (float)smem[(rh * 32 + r) * EPI_STRIDE + c];
                }
                if (gprev >= 0) atomicAdd(&G[(size_t)gprev * GFEAT + colg], run);
            }
        }
        __syncthreads();
    }
}

// ---------------------------------------------------------------------------
// edge aggregation + combine, both branches (blockIdx.y):
// H[v] = relu(sum_{e: dst=v} hW[src[e]] + b) + res[v]
// one wave per dst node; lane covers 8 feats (16B), half-waves cover 2 edges.
// (R3 structure: ~memory-system ceiling for this access pattern.)
// ---------------------------------------------------------------------------
__global__ __launch_bounds__(256) void agg_combine2_kernel(
    const bf16* __restrict__ hW0, const bf16* __restrict__ hW1,
    const int* __restrict__ csr0, const int* __restrict__ csr1,
    const int* __restrict__ offs0, const int* __restrict__ offs1,
    const float* __restrict__ bias0, const float* __restrict__ bias1,
    const bf16* __restrict__ res0, const bf16* __restrict__ res1,
    bf16* __restrict__ H0, bf16* __restrict__ H1, int n_nodes) {
    const bf16* hW = blockIdx.y ? hW1 : hW0;
    const int* csr_src = blockIdx.y ? csr1 : csr0;
    const int* offsets = blockIdx.y ? offs1 : offs0;
    const float* bias = blockIdx.y ? bias1 : bias0;
    const bf16* res = blockIdx.y ? res1 : res0;
    bf16* H = blockIdx.y ? H1 : H0;

    int wave = threadIdx.x >> 6;
    int lane = threadIdx.x & 63;
    int node = blockIdx.x * 4 + wave;
    if (node >= n_nodes) return;
    int beg = offsets[node], end = offsets[node + 1];
    const int half = lane >> 5;
    const int fo   = (lane & 31) * 8;

    float acc[8] = {};
    int j = beg;
    for (; j + 6 + half < end; j += 8) {
        int s0 = csr_src[j + half];
        int s1 = csr_src[j + 2 + half];
        int s2 = csr_src[j + 4 + half];
        int s3 = csr_src[j + 6 + half];
        bf16x8 v0 = *(const bf16x8*)&hW[(size_t)s0 * DD + fo];
        bf16x8 v1 = *(const bf16x8*)&hW[(size_t)s1 * DD + fo];
        bf16x8 v2 = *(const bf16x8*)&hW[(size_t)s2 * DD + fo];
        bf16x8 v3 = *(const bf16x8*)&hW[(size_t)s3 * DD + fo];
#pragma unroll
        for (int q = 0; q < 8; q++) acc[q] += (float)v0[q];
#pragma unroll
        for (int q = 0; q < 8; q++) acc[q] += (float)v1[q];
#pragma unroll
        for (int q = 0; q < 8; q++) acc[q] += (float)v2[q];
#pragma unroll
        for (int q = 0; q < 8; q++) acc[q] += (float)v3[q];
    }
    for (; j + half < end; j += 2) {
        int s = csr_src[j + half];
        bf16x8 v = *(const bf16x8*)&hW[(size_t)s * DD + fo];
#pragma unroll
        for (int q = 0; q < 8; q++) acc[q] += (float)v[q];
    }
#pragma unroll
    for (int q = 0; q < 8; q++) acc[q] += __shfl_xor(acc[q], 32, 64);

    if (half == 0) {
        float4 b0 = *(const float4*)&bias[fo];
        float4 b1 = *(const float4*)&bias[fo + 4];
        bf16x8 rv = *(const bf16x8*)&res[(size_t)node * DD + fo];
        bf16x8 o;
        o[0] = (bf16)(fmaxf(acc[0] + b0.x, 0.f) + (float)rv[0]);
        o[1] = (bf16)(fmaxf(acc[1] + b0.y, 0.f) + (float)rv[1]);
        o[2] = (bf16)(fmaxf(acc[2] + b0.z, 0.f) + (float)rv[2]);
        o[3] = (bf16)(fmaxf(acc[3] + b0.w, 0.f) + (float)rv[3]);
        o[4] = (bf16)(fmaxf(acc[4] + b1.x, 0.f) + (float)rv[4]);
        o[5] = (bf16)(fmaxf(acc[5] + b1.y, 0.f) + (float)rv[5]);
        o[6] = (bf16)(fmaxf(acc[6] + b1.z, 0.f) + (float)rv[6]);
        o[7] = (bf16)(fmaxf(acc[7] + b1.w, 0.f) + (float)rv[7]);
        *(bf16x8*)&H[(size_t)node * DD + fo] = o;
    }
}

__global__ __launch_bounds__(256) void predictor_kernel(const float* __restrict__ G1,
                                                        const float* __restrict__ G2,
                                                        const float* __restrict__ Wp,
                                                        const float* __restrict__ bp,
                                                        float* __restrict__ out) {
    int i = blockIdx.x * 256 + threadIdx.x;
    if (i >= NG) return;
    float acc = bp[0];
    for (int f = 0; f < GFEAT; f++)
        acc += (G1[i * GFEAT + f] + G2[i * GFEAT + f]) * Wp[f];
    out[i] = acc;
}

extern "C" void kernel_launch(void* const* d_in, const int* in_sizes, int n_in,
                              void* d_out, int out_size, void* d_ws, size_t ws_size,
                              hipStream_t stream) {
    const float* X1   = (const float*)d_in[0];
    const float* X2   = (const float*)d_in[2];
    const int*   src1 = (const int*)d_in[4];
    const int*   dst1 = (const int*)d_in[5];
    const int*   gid1 = (const int*)d_in[6];
    const int*   src2 = (const int*)d_in[7];
    const int*   dst2 = (const int*)d_in[8];
    const int*   gid2 = (const int*)d_in[9];
    const float* W1  = (const float*)d_in[10]; const float* b1  = (const float*)d_in[11];
    const float* Wr1 = (const float*)d_in[12]; const float* br1 = (const float*)d_in[13];
    const float* W2  = (const float*)d_in[14]; const float* b2  = (const float*)d_in[15];
    const float* Wr2 = (const float*)d_in[16]; const float* br2 = (const float*)d_in[17];
    const float* Ri1 = (const float*)d_in[18]; const float* rbi1 = (const float*)d_in[19];
    const float* Ro1 = (const float*)d_in[20]; const float* rbo1 = (const float*)d_in[21];
    const float* Ri2 = (const float*)d_in[22]; const float* rbi2 = (const float*)d_in[23];
    const float* Ro2 = (const float*)d_in[24]; const float* rbo2 = (const float*)d_in[25];
    const float* Wp  = (const float*)d_in[26]; const float* bp  = (const float*)d_in[27];

    // workspace layout (per-branch buffers; lifetime-disjoint aliases)
    const size_t NB = (size_t)NN * DD * sizeof(bf16);   // 25.6 MB
    char* p = (char*)d_ws;
    bf16* XbH1 = (bf16*)p; p += NB;     // Xb1 (conv->fused), then H1 (agg->Ri)
    bf16* XbH2 = (bf16*)p; p += NB;
    bf16* hWR1 = (bf16*)p; p += NB;     // eb1 (CSR), then hW1 (fused->agg), then R1 (Ri->Ro)
    bf16* hWR2 = (bf16*)p; p += NB;
    bf16* res1 = (bf16*)p; p += NB;     // res (fused->agg)
    bf16* res2 = (bf16*)p; p += NB;
    float* G1  = (float*)p; p += (size_t)NG * GFEAT * sizeof(float);
    float* G2  = (float*)p; p += (size_t)NG * GFEAT * sizeof(float);
    // 8 weight mats; order: W1,Wr1,Ri1,Ro1,W2,Wr2,Ri2,Ro2 (W|Wr contiguous = fused Bt)
    bf16* Wbase = (bf16*)p; p += 8 * 65536 * sizeof(bf16);
    int* offs1 = (int*)p; p += (NN + 1) * sizeof(int);
    int* offs2 = (int*)p; p += (NN + 1) * sizeof(int);
    int* cnt1  = (int*)p; p += NBKT * NCHUNK * sizeof(int);
    int* cnt2  = (int*)p; p += NBKT * NCHUNK * sizeof(int);
    int* csr1  = (int*)p; p += NE * sizeof(int);
    int* csr2  = (int*)p; p += NE * sizeof(int);
    int2* eb1 = (int2*)hWR1;   // live only during CSR build (before fused writes hW)
    int2* eb2 = (int2*)hWR2;

    zero_g_kernel<<<dim3((NG * GFEAT + 255) / 256, 2), 256, 0, stream>>>(G1, G2);
    conv_w8_kernel<<<dim3(256, 8), 256, 0, stream>>>(W1, Wr1, Ri1, Ro1, W2, Wr2, Ri2, Ro2, Wbase);
    conv_x2_kernel<<<dim3((NN * DD / 4 + 255) / 256, 2), 256, 0, stream>>>(
        X1, X2, XbH1, XbH2, NN * DD / 4);

    // CSR build (both branches): two-level counting sort, no global atomics
    csr_coarse_hist_kernel<<<dim3(NCHUNK, 2), 256, 0, stream>>>(dst1, dst2, cnt1, cnt2);
    csr_scan_kernel<<<dim3(1, 2), 1024, 0, stream>>>(cnt1, cnt2, offs1, offs2);
    csr_partition_kernel<<<dim3(NCHUNK, 2), 256, 0, stream>>>(
        src1, src2, dst1, dst2, cnt1, cnt2, eb1, eb2);
    csr_bucket_sort_kernel<<<dim3(NBKT, 2), 512, 0, stream>>>(
        cnt1, cnt2, eb1, eb2, offs1, offs2, csr1, csr2);

    // hW = X @ W ; res = relu(X @ Wr + br)          [both branches]
    mfma_gemm_fused2_kernel<<<dim3(49 * 32, 2), 256, 0, stream>>>(
        XbH1, XbH2, Wbase + 0 * 65536, Wbase + 4 * 65536, br1, br2,
        hWR1, hWR2, res1, res2, NN);
    // H = relu(agg + b) + res                       [both branches]
    agg_combine2_kernel<<<dim3((NN + 3) / 4, 2), 256, 0, stream>>>(
        hWR1, hWR2, csr1, csr2, offs1, offs2, b1, b2, res1, res2, XbH1, XbH2, NN);
    // R = relu(H @ Ri + rbi)                        [both branches]
    mfma_gemm2_kernel<<<dim3(49 * 16, 2), 256, 0, stream>>>(
        XbH1, XbH2, Wbase + 2 * 65536, Wbase + 6 * 65536, rbi1, rbi2,
        hWR1, hWR2, NN, DD, 1);
    // G = segment_sum(R @ Ro + rbo) fused           [both branches]
    mfma_gemm_reduce2_kernel<<<dim3(49 * 16, 2), 256, 0, stream>>>(
        hWR1, hWR2, Wbase + 3 * 65536, Wbase + 7 * 65536, rbo1, rbo2,
        gid1, gid2, G1, G2, NN, GFEAT);

    predictor_kernel<<<(NG + 255) / 256, 256, 0, stream>>>(G1, G2, Wp, bp, (float*)d_out);
}

// Round 6
// 544.557 us; speedup vs baseline: 1.9264x; 1.0236x over previous
//
#include <hip/hip_runtime.h>

// Problem constants (fixed by reference)
#define NN 50000      // nodes
#define NE 800000     // edges
#define DD 256        // node feat dim
#define GFEAT 200     // graph feat dim
#define NG 512        // graphs

typedef __bf16 bf16;
typedef bf16 bf16x4 __attribute__((ext_vector_type(4)));
typedef bf16 bf16x8 __attribute__((ext_vector_type(8)));
typedef float f32x4 __attribute__((ext_vector_type(4)));

// async global->LDS, 16B per lane. HW dest = wave-uniform base + lane*16.
__device__ __forceinline__ void gl_lds16(const bf16* g, bf16* l) {
    __builtin_amdgcn_global_load_lds(
        (const __attribute__((address_space(1))) uint32_t*)(g),
        (__attribute__((address_space(3))) uint32_t*)(l), 16, 0, 0);
}

// BK=64 LDS tile [R][64]; 16B chunk c holds global chunk c^((row>>1)&7)
__device__ __forceinline__ bf16x8 frag_ld64(const bf16* s, int R, int C) {
    return *(const bf16x8*)&s[R * 64 + ((C ^ ((R >> 1) & 7)) << 3)];
}

#define EPI_STRIDE 136   // bf16 elems; 272 B row stride (16B-aligned, bank-shift 4/row)

// ---------------------------------------------------------------------------
// weight conversion: 8 fp32 [K][N] -> bf16 [256][256] = [n][k] transposed, padded
// ---------------------------------------------------------------------------
__global__ __launch_bounds__(256) void conv_w8_kernel(
    const float* __restrict__ w0, const float* __restrict__ w1,
    const float* __restrict__ w2, const float* __restrict__ w3,
    const float* __restrict__ w4, const float* __restrict__ w5,
    const float* __restrict__ w6, const float* __restrict__ w7,
    bf16* __restrict__ out_base) {
    const float* ws[8] = {w0, w1, w2, w3, w4, w5, w6, w7};
    const int Ns[8] = {DD, DD, DD, GFEAT, DD, DD, DD, GFEAT};
    int m = blockIdx.y;
    const float* in = ws[m];
    int N = Ns[m];
    int idx = blockIdx.x * 256 + threadIdx.x;   // 0..65535 over [n][k]
    int n = idx >> 8, k = idx & 255;
    float v = (n < N) ? in[k * N + n] : 0.f;
    out_base[(size_t)m * 65536 + idx] = (bf16)v;
}

__global__ __launch_bounds__(256) void zero_g_kernel(float* __restrict__ G0,
                                                     float* __restrict__ G1) {
    float* G = blockIdx.y ? G1 : G0;
    int i = blockIdx.x * 256 + threadIdx.x;
    if (i < NG * GFEAT) G[i] = 0.f;
}

// ---------------------------------------------------------------------------
// CSR build: two-level counting sort, zero global atomics, O(1) reads/edge.
// ---------------------------------------------------------------------------
#define NBKT   128
#define NPB    391            // ceil(NN / NBKT); 128*391 = 50048
#define NCHUNK 256
#define CE     ((NE + NCHUNK - 1) / NCHUNK)   // 3125 edges per chunk

__global__ __launch_bounds__(256) void csr_coarse_hist_kernel(
    const int* __restrict__ d0, const int* __restrict__ d1,
    int* __restrict__ cnt0, int* __restrict__ cnt1) {
    const int blk = blockIdx.x, t = threadIdx.x;
    const int* dst = blockIdx.y ? d1 : d0;
    int* cnt = blockIdx.y ? cnt1 : cnt0;
    __shared__ int hist[NBKT];
    if (t < NBKT) hist[t] = 0;
    __syncthreads();
    const int e0 = blk * CE;
    const int e1 = (e0 + CE < NE) ? e0 + CE : NE;
    for (int e = e0 + t; e < e1; e += 256)
        atomicAdd(&hist[dst[e] / NPB], 1);
    __syncthreads();
    if (t < NBKT) cnt[t * NCHUNK + blk] = hist[t];   // bucket-major
}

__global__ __launch_bounds__(1024) void csr_scan_kernel(
    int* __restrict__ cnt0, int* __restrict__ cnt1,
    int* __restrict__ offs0, int* __restrict__ offs1) {
    int* cnt = blockIdx.y ? cnt1 : cnt0;
    const int t = threadIdx.x;
    const int PER = (NBKT * NCHUNK) / 1024;   // 32
    int v[PER];
    int sum = 0;
    const int base = t * PER;
#pragma unroll
    for (int i = 0; i < PER; i += 4) {
        int4 q = *(const int4*)&cnt[base + i];
        v[i] = q.x; v[i + 1] = q.y; v[i + 2] = q.z; v[i + 3] = q.w;
        sum += q.x + q.y + q.z + q.w;
    }
    __shared__ int s[1024];
    s[t] = sum;
    __syncthreads();
    for (int off = 1; off < 1024; off <<= 1) {
        int a = (t >= off) ? s[t - off] : 0;
        __syncthreads();
        s[t] += a;
        __syncthreads();
    }
    int run = s[t] - sum;   // exclusive prefix of this thread's chunk
#pragma unroll
    for (int i = 0; i < PER; i++) { int c = v[i]; cnt[base + i] = run; run += c; }
    if (t == 0) (blockIdx.y ? offs1 : offs0)[NN] = NE;
}

__global__ __launch_bounds__(256) void csr_partition_kernel(
    const int* __restrict__ sA, const int* __restrict__ sB,
    const int* __restrict__ d0, const int* __restrict__ d1,
    const int* __restrict__ cnt0, const int* __restrict__ cnt1,
    int2* __restrict__ eb0, int2* __restrict__ eb1) {
    const int blk = blockIdx.x, t = threadIdx.x;
    const int* src = blockIdx.y ? sB : sA;
    const int* dst = blockIdx.y ? d1 : d0;
    const int* cnt = blockIdx.y ? cnt1 : cnt0;
    int2* eb = blockIdx.y ? eb1 : eb0;
    __shared__ int cur[NBKT];
    if (t < NBKT) cur[t] = cnt[t * NCHUNK + blk];   // this chunk's start in each bucket
    __syncthreads();
    const int e0 = blk * CE;
    const int e1 = (e0 + CE < NE) ? e0 + CE : NE;
    for (int e = e0 + t; e < e1; e += 256) {
        int d = dst[e], s = src[e];
        int pos = atomicAdd(&cur[d / NPB], 1);      // LDS atomic, range disjoint per block
        eb[pos] = make_int2(s, d);
    }
}

__global__ __launch_bounds__(512) void csr_bucket_sort_kernel(
    const int* __restrict__ cnt0, const int* __restrict__ cnt1,
    const int2* __restrict__ eb0, const int2* __restrict__ eb1,
    int* __restrict__ offs0, int* __restrict__ offs1,
    int* __restrict__ csr0, int* __restrict__ csr1) {
    const int b = blockIdx.x, t = threadIdx.x;
    const int* cnt = blockIdx.y ? cnt1 : cnt0;
    const int2* eb = blockIdx.y ? eb1 : eb0;
    int* offs = blockIdx.y ? offs1 : offs0;
    int* csr = blockIdx.y ? csr1 : csr0;
    const int lo = b * NPB;
    const int ncnt = (NN - lo < NPB) ? (NN - lo) : NPB;
    const int beg = cnt[b * NCHUNK];
    const int end = (b == NBKT - 1) ? NE : cnt[(b + 1) * NCHUNK];

    __shared__ int hist[NPB];
    __shared__ int s[512];
    if (t < NPB) hist[t] = 0;
    __syncthreads();
    for (int i = beg + t; i < end; i += 512)
        atomicAdd(&hist[eb[i].y - lo], 1);
    __syncthreads();

    int h = (t < NPB) ? hist[t] : 0;
    s[t] = h;
    __syncthreads();
    for (int off = 1; off < 512; off <<= 1) {
        int a = (t >= off) ? s[t - off] : 0;
        __syncthreads();
        s[t] += a;
        __syncthreads();
    }
    int excl = s[t] - h;
    __syncthreads();
    if (t < NPB) hist[t] = excl;                 // local cursors
    if (t < ncnt) offs[lo + t] = beg + excl;     // final global offsets
    __syncthreads();

    for (int i = beg + t; i < end; i += 512) {
        int2 v = eb[i];
        int pos = atomicAdd(&hist[v.y - lo], 1);
        csr[beg + pos] = v.x;                    // contiguous ~25 KB region per block
    }
}

// ---------------------------------------------------------------------------
// 256x128-tile bf16 MFMA GEMM family, 512 threads (8 waves = 4 row x 2 col),
// BK=64, K=256, both branches via blockIdx.y, XCD-swizzled block decode
// (all col-blocks of a row-panel share id mod 8 -> same XCD).
// LDS: As 256x64 (32KB) | Bs 128x64 (16KB); epilogue slab reuses As.
// ---------------------------------------------------------------------------

// Generic: C[M, col0..col0+128) = A[M,256] @ Bt[128r,256]^T (+bias<Nb)(+relu)
// grid (25*16, 2): r8=lid&7, cc=(lid>>3)&1, g=lid>>4.
__global__ __launch_bounds__(512) void mfma_gemm2_kernel(
    const bf16* __restrict__ A0, const bf16* __restrict__ A1,
    const bf16* __restrict__ Bt0, const bf16* __restrict__ Bt1,
    const float* __restrict__ bias0, const float* __restrict__ bias1,
    bf16* __restrict__ out0, bf16* __restrict__ out1,
    int M, int Nb, int do_relu) {
    const int lid = blockIdx.x;
    const int r8 = lid & 7, cc = (lid >> 3) & 1, g = lid >> 4;
    const int row_blk = g * 8 + r8;
    if (row_blk * 256 >= M) return;
    const bf16* A = blockIdx.y ? A1 : A0;
    const bf16* Bt = blockIdx.y ? Bt1 : Bt0;
    const float* bias = blockIdx.y ? bias1 : bias0;
    bf16* out = blockIdx.y ? out1 : out0;

    __shared__ bf16 smem[24576];       // As 16384 | Bs 8192
    bf16* As = smem;
    bf16* Bs = smem + 16384;

    const int t    = threadIdx.x;
    const int lane = t & 63;
    const int w    = t >> 6;
    const int row0 = row_blk * 256;
    const int col0 = cc * 128;

    f32x4 acc[4][4] = {};
    const int wm = (w >> 1) * 64, wn = (w & 1) * 64;
    const int fm = lane & 15, fC = lane >> 4;

    for (int k0 = 0; k0 < 256; k0 += 64) {
#pragma unroll
        for (int r = 0; r < 4; r++) {            // As: 2048 chunks
            int flat = r * 512 + t;
            int fr = flat >> 3, fc = flat & 7;
            int fcg = fc ^ ((fr >> 1) & 7);
            int arow = row0 + fr;
            if (arow > M - 1) arow = M - 1;
            gl_lds16(&A[(size_t)arow * 256 + k0 + fcg * 8], &As[flat * 8]);
        }
#pragma unroll
        for (int r = 0; r < 2; r++) {            // Bs: 1024 chunks
            int flat = r * 512 + t;
            int fr = flat >> 3, fc = flat & 7;
            int fcg = fc ^ ((fr >> 1) & 7);
            int brow = col0 + fr;                // Bt padded to 256 rows
            gl_lds16(&Bt[(size_t)brow * 256 + k0 + fcg * 8], &Bs[flat * 8]);
        }
        __syncthreads();
#pragma unroll
        for (int s = 0; s < 2; s++) {
            bf16x8 af[4], bfr[4];
#pragma unroll
            for (int i = 0; i < 4; i++) af[i] = frag_ld64(As, wm + i * 16 + fm, s * 4 + fC);
#pragma unroll
            for (int i = 0; i < 4; i++) bfr[i] = frag_ld64(Bs, wn + i * 16 + fm, s * 4 + fC);
#pragma unroll
            for (int i = 0; i < 4; i++)
#pragma unroll
                for (int j = 0; j < 4; j++)
                    acc[i][j] = __builtin_amdgcn_mfma_f32_16x16x32_bf16(af[i], bfr[j], acc[i][j], 0, 0, 0);
        }
        __syncthreads();
    }

    float bv[4];
#pragma unroll
    for (int j = 0; j < 4; j++) {
        int col = col0 + wn + fm + j * 16;
        bv[j] = (col < Nb) ? bias[col] : 0.f;
    }

#pragma unroll
    for (int p = 0; p < 4; p++) {                // 4 passes of 64 rows
        if ((w >> 1) == p) {
#pragma unroll
            for (int i = 0; i < 4; i++)
#pragma unroll
                for (int j = 0; j < 4; j++)
#pragma unroll
                    for (int r2 = 0; r2 < 4; r2++) {
                        int rl = i * 16 + (lane >> 4) * 4 + r2;   // 0..63
                        int cl = wn + fm + j * 16;                // 0..127
                        float v = acc[i][j][r2] + bv[j];
                        if (do_relu) v = fmaxf(v, 0.f);
                        smem[rl * EPI_STRIDE + cl] = (bf16)v;
                    }
        }
        __syncthreads();
#pragma unroll
        for (int q = 0; q < 2; q++) {            // 1024 slots of 8 bf16
            int flat = q * 512 + t;
            int rl = flat >> 4, seg = flat & 15;
            int grow = row0 + p * 64 + rl;
            if (grow < M)
                *(bf16x8*)&out[(size_t)grow * 256 + col0 + seg * 8] =
                    *(const bf16x8*)&smem[rl * EPI_STRIDE + seg * 8];
        }
        __syncthreads();
    }
}

// Fused conv + W|Wr GEMM: A is fp32 X (converted during reg-staged A load).
// Bt2 512x256: cols 0-255 -> out_lo (no act), 256-511 -> out_hi=relu(.+bias_hi).
// grid (25*32, 2): r8=lid&7, cc=(lid>>3)&3, g=lid>>5.
__global__ __launch_bounds__(512) void mfma_gemm_fusedconv2_kernel(
    const float* __restrict__ X0, const float* __restrict__ X1,
    const bf16* __restrict__ Bt2_0, const bf16* __restrict__ Bt2_1,
    const float* __restrict__ bh0, const float* __restrict__ bh1,
    bf16* __restrict__ lo0, bf16* __restrict__ lo1,
    bf16* __restrict__ hi0, bf16* __restrict__ hi1, int M) {
    const int lid = blockIdx.x;
    const int r8 = lid & 7, cc = (lid >> 3) & 3, g = lid >> 5;
    const int row_blk = g * 8 + r8;
    if (row_blk * 256 >= M) return;
    const float* Xf = blockIdx.y ? X1 : X0;
    const bf16* Bt2 = blockIdx.y ? Bt2_1 : Bt2_0;
    const float* bias_hi = blockIdx.y ? bh1 : bh0;
    bf16* out_lo = blockIdx.y ? lo1 : lo0;
    bf16* out_hi = blockIdx.y ? hi1 : hi0;

    __shared__ bf16 smem[24576];
    bf16* As = smem;
    bf16* Bs = smem + 16384;

    const int t    = threadIdx.x;
    const int lane = t & 63;
    const int w    = t >> 6;
    const int row0 = row_blk * 256;
    const int col0 = cc * 128;   // 0..384

    f32x4 acc[4][4] = {};
    const int wm = (w >> 1) * 64, wn = (w & 1) * 64;
    const int fm = lane & 15, fC = lane >> 4;

    for (int k0 = 0; k0 < 256; k0 += 64) {
#pragma unroll
        for (int r = 0; r < 2; r++) {            // Bs async first
            int flat = r * 512 + t;
            int fr = flat >> 3, fc = flat & 7;
            int fcg = fc ^ ((fr >> 1) & 7);
            int brow = col0 + fr;
            gl_lds16(&Bt2[(size_t)brow * 256 + k0 + fcg * 8], &Bs[flat * 8]);
        }
#pragma unroll
        for (int r = 0; r < 4; r++) {            // As: fp32 load + cvt + swizzled write
            int flat = r * 512 + t;
            int fr = flat >> 3, fc = flat & 7;
            int arow = row0 + fr;
            if (arow > M - 1) arow = M - 1;
            const float* gsrc = &Xf[(size_t)arow * 256 + k0 + fc * 8];
            float4 u0 = *(const float4*)gsrc;
            float4 u1 = *(const float4*)(gsrc + 4);
            bf16x8 o;
            o[0] = (bf16)u0.x; o[1] = (bf16)u0.y; o[2] = (bf16)u0.z; o[3] = (bf16)u0.w;
            o[4] = (bf16)u1.x; o[5] = (bf16)u1.y; o[6] = (bf16)u1.z; o[7] = (bf16)u1.w;
            *(bf16x8*)&As[fr * 64 + (fc ^ ((fr >> 1) & 7)) * 8] = o;
        }
        __syncthreads();
#pragma unroll
        for (int s = 0; s < 2; s++) {
            bf16x8 af[4], bfr[4];
#pragma unroll
            for (int i = 0; i < 4; i++) af[i] = frag_ld64(As, wm + i * 16 + fm, s * 4 + fC);
#pragma unroll
            for (int i = 0; i < 4; i++) bfr[i] = frag_ld64(Bs, wn + i * 16 + fm, s * 4 + fC);
#pragma unroll
            for (int i = 0; i < 4; i++)
#pragma unroll
                for (int j = 0; j < 4; j++)
                    acc[i][j] = __builtin_amdgcn_mfma_f32_16x16x32_bf16(af[i], bfr[j], acc[i][j], 0, 0, 0);
        }
        __syncthreads();
    }

    const bool hi = (col0 >= 256);          // block-uniform
    bf16* out = hi ? out_hi : out_lo;
    const int cb = hi ? col0 - 256 : col0;

    float bv[4];
#pragma unroll
    for (int j = 0; j < 4; j++) {
        int col = cb + wn + fm + j * 16;
        bv[j] = hi ? bias_hi[col] : 0.f;
    }

#pragma unroll
    for (int p = 0; p < 4; p++) {
        if ((w >> 1) == p) {
#pragma unroll
            for (int i = 0; i < 4; i++)
#pragma unroll
                for (int j = 0; j < 4; j++)
#pragma unroll
                    for (int r2 = 0; r2 < 4; r2++) {
                        int rl = i * 16 + (lane >> 4) * 4 + r2;
                        int cl = wn + fm + j * 16;
                        float v = acc[i][j][r2] + bv[j];
                        if (hi) v = fmaxf(v, 0.f);
                        smem[rl * EPI_STRIDE + cl] = (bf16)v;
                    }
        }
        __syncthreads();
#pragma unroll
        for (int q = 0; q < 2; q++) {
            int flat = q * 512 + t;
            int rl = flat >> 4, seg = flat & 15;
            int grow = row0 + p * 64 + rl;
            if (grow < M)
                *(bf16x8*)&out[(size_t)grow * 256 + cb + seg * 8] =
                    *(const bf16x8*)&smem[rl * EPI_STRIDE + seg * 8];
        }
        __syncthreads();
    }
}

// Ro GEMM + per-graph segment reduce fused. P-tile -> LDS; per-column fp32
// segment sums over sorted gids atomicAdd'ed into G. grid (25*16, 2).
__global__ __launch_bounds__(512) void mfma_gemm_reduce2_kernel(
    const bf16* __restrict__ A0, const bf16* __restrict__ A1,
    const bf16* __restrict__ Bt0, const bf16* __restrict__ Bt1,
    const float* __restrict__ bias0, const float* __restrict__ bias1,
    const int* __restrict__ gid0, const int* __restrict__ gid1,
    float* __restrict__ G0, float* __restrict__ G1, int M, int Nb) {
    const int lid = blockIdx.x;
    const int r8 = lid & 7, cc = (lid >> 3) & 1, g = lid >> 4;
    const int row_blk = g * 8 + r8;
    if (row_blk * 256 >= M) return;
    const bf16* A = blockIdx.y ? A1 : A0;
    const bf16* Bt = blockIdx.y ? Bt1 : Bt0;
    const float* bias = blockIdx.y ? bias1 : bias0;
    const int* gids = blockIdx.y ? gid1 : gid0;
    float* G = blockIdx.y ? G1 : G0;

    __shared__ bf16 smem[24576];
    bf16* As = smem;
    bf16* Bs = smem + 16384;

    const int t    = threadIdx.x;
    const int lane = t & 63;
    const int w    = t >> 6;
    const int row0 = row_blk * 256;
    const int col0 = cc * 128;

    f32x4 acc[4][4] = {};
    const int wm = (w >> 1) * 64, wn = (w & 1) * 64;
    const int fm = lane & 15, fC = lane >> 4;

    for (int k0 = 0; k0 < 256; k0 += 64) {
#pragma unroll
        for (int r = 0; r < 4; r++) {
            int flat = r * 512 + t;
            int fr = flat >> 3, fc = flat & 7;
            int fcg = fc ^ ((fr >> 1) & 7);
            int arow = row0 + fr;
            if (arow > M - 1) arow = M - 1;
            gl_lds16(&A[(size_t)arow * 256 + k0 + fcg * 8], &As[flat * 8]);
        }
#pragma unroll
        for (int r = 0; r < 2; r++) {
            int flat = r * 512 + t;
            int fr = flat >> 3, fc = flat & 7;
            int fcg = fc ^ ((fr >> 1) & 7);
            int brow = col0 + fr;
            gl_lds16(&Bt[(size_t)brow * 256 + k0 + fcg * 8], &Bs[flat * 8]);
        }
        __syncthreads();
#pragma unroll
        for (int s = 0; s < 2; s++) {
            bf16x8 af[4], bfr[4];
#pragma unroll
            for (int i = 0; i < 4; i++) af[i] = frag_ld64(As, wm + i * 16 + fm, s * 4 + fC);
#pragma unroll
            for (int i = 0; i < 4; i++) bfr[i] = frag_ld64(Bs, wn + i * 16 + fm, s * 4 + fC);
#pragma unroll
            for (int i = 0; i < 4; i++)
#pragma unroll
                for (int j = 0; j < 4; j++)
                    acc[i][j] = __builtin_amdgcn_mfma_f32_16x16x32_bf16(af[i], bfr[j], acc[i][j], 0, 0, 0);
        }
        __syncthreads();
    }

    float bv[4];
#pragma unroll
    for (int j = 0; j < 4; j++) {
        int col = col0 + wn + fm + j * 16;
        bv[j] = (col < Nb) ? bias[col] : 0.f;
    }

#pragma unroll
    for (int p = 0; p < 4; p++) {
        if ((w >> 1) == p) {
#pragma unroll
            for (int i = 0; i < 4; i++)
#pragma unroll
                for (int j = 0; j < 4; j++)
#pragma unroll
                    for (int r2 = 0; r2 < 4; r2++) {
                        int rl = i * 16 + (lane >> 4) * 4 + r2;
                        int cl = wn + fm + j * 16;
                        smem[rl * EPI_STRIDE + cl] = (bf16)(acc[i][j][r2] + bv[j]);
                    }
        }
        __syncthreads();
        // segment reduce: 4 threads per column, 16 rows each; sorted gids ->
        // flush partial into G on boundary (fp32 atomic, device scope).
        {
            int c = t & 127, rh = t >> 7;        // rh 0..3
            int colg = col0 + c;
            if (colg < Nb) {
                float run = 0.f;
                int gprev = -1;
                for (int r = 0; r < 16; r++) {
                    int grow = row0 + p * 64 + rh * 16 + r;
                    if (grow >= M) break;
                    int gg = gids[grow];
                    if (gg != gprev) {
                        if (gprev >= 0) atomicAdd(&G[(size_t)gprev * GFEAT + colg], run);
                        run = 0.f;
                        gprev = gg;
                    }
                    run += (float)smem[(rh * 16 + r) * EPI_STRIDE + c];
                }
                if (gprev >= 0) atomicAdd(&G[(size_t)gprev * GFEAT + colg], run);
            }
        }
        __syncthreads();
    }
}

// ---------------------------------------------------------------------------
// edge aggregation + combine, both branches (blockIdx.y):
// H[v] = relu(sum_{e: dst=v} hW[src[e]] + b) + res[v]
// one wave per dst node; lane covers 8 feats (16B), half-waves cover 2 edges.
// (memory-system ceiling for this access pattern: ~3.9 TB/s, 3 structures tried)
// ---------------------------------------------------------------------------
__global__ __launch_bounds__(256) void agg_combine2_kernel(
    const bf16* __restrict__ hW0, const bf16* __restrict__ hW1,
    const int* __restrict__ csr0, const int* __restrict__ csr1,
    const int* __restrict__ offs0, const int* __restrict__ offs1,
    const float* __restrict__ bias0, const float* __restrict__ bias1,
    const bf16* __restrict__ res0, const bf16* __restrict__ res1,
    bf16* __restrict__ H0, bf16* __restrict__ H1, int n_nodes) {
    const bf16* hW = blockIdx.y ? hW1 : hW0;
    const int* csr_src = blockIdx.y ? csr1 : csr0;
    const int* offsets = blockIdx.y ? offs1 : offs0;
    const float* bias = blockIdx.y ? bias1 : bias0;
    const bf16* res = blockIdx.y ? res1 : res0;
    bf16* H = blockIdx.y ? H1 : H0;

    int wave = threadIdx.x >> 6;
    int lane = threadIdx.x & 63;
    int node = blockIdx.x * 4 + wave;
    if (node >= n_nodes) return;
    int beg = offsets[node], end = offsets[node + 1];
    const int half = lane >> 5;
    const int fo   = (lane & 31) * 8;

    float acc[8] = {};
    int j = beg;
    for (; j + 6 + half < end; j += 8) {
        int s0 = csr_src[j + half];
        int s1 = csr_src[j + 2 + half];
        int s2 = csr_src[j + 4 + half];
        int s3 = csr_src[j + 6 + half];
        bf16x8 v0 = *(const bf16x8*)&hW[(size_t)s0 * DD + fo];
        bf16x8 v1 = *(const bf16x8*)&hW[(size_t)s1 * DD + fo];
        bf16x8 v2 = *(const bf16x8*)&hW[(size_t)s2 * DD + fo];
        bf16x8 v3 = *(const bf16x8*)&hW[(size_t)s3 * DD + fo];
#pragma unroll
        for (int q = 0; q < 8; q++) acc[q] += (float)v0[q];
#pragma unroll
        for (int q = 0; q < 8; q++) acc[q] += (float)v1[q];
#pragma unroll
        for (int q = 0; q < 8; q++) acc[q] += (float)v2[q];
#pragma unroll
        for (int q = 0; q < 8; q++) acc[q] += (float)v3[q];
    }
    for (; j + half < end; j += 2) {
        int s = csr_src[j + half];
        bf16x8 v = *(const bf16x8*)&hW[(size_t)s * DD + fo];
#pragma unroll
        for (int q = 0; q < 8; q++) acc[q] += (float)v[q];
    }
#pragma unroll
    for (int q = 0; q < 8; q++) acc[q] += __shfl_xor(acc[q], 32, 64);

    if (half == 0) {
        float4 b0 = *(const float4*)&bias[fo];
        float4 b1 = *(const float4*)&bias[fo + 4];
        bf16x8 rv = *(const bf16x8*)&res[(size_t)node * DD + fo];
        bf16x8 o;
        o[0] = (bf16)(fmaxf(acc[0] + b0.x, 0.f) + (float)rv[0]);
        o[1] = (bf16)(fmaxf(acc[1] + b0.y, 0.f) + (float)rv[1]);
        o[2] = (bf16)(fmaxf(acc[2] + b0.z, 0.f) + (float)rv[2]);
        o[3] = (bf16)(fmaxf(acc[3] + b0.w, 0.f) + (float)rv[3]);
        o[4] = (bf16)(fmaxf(acc[4] + b1.x, 0.f) + (float)rv[4]);
        o[5] = (bf16)(fmaxf(acc[5] + b1.y, 0.f) + (float)rv[5]);
        o[6] = (bf16)(fmaxf(acc[6] + b1.z, 0.f) + (float)rv[6]);
        o[7] = (bf16)(fmaxf(acc[7] + b1.w, 0.f) + (float)rv[7]);
        *(bf16x8*)&H[(size_t)node * DD + fo] = o;
    }
}

__global__ __launch_bounds__(256) void predictor_kernel(const float* __restrict__ G1,
                                                        const float* __restrict__ G2,
                                                        const float* __restrict__ Wp,
                                                        const float* __restrict__ bp,
                                                        float* __restrict__ out) {
    int i = blockIdx.x * 256 + threadIdx.x;
    if (i >= NG) return;
    float acc = bp[0];
    for (int f = 0; f < GFEAT; f++)
        acc += (G1[i * GFEAT + f] + G2[i * GFEAT + f]) * Wp[f];
    out[i] = acc;
}

extern "C" void kernel_launch(void* const* d_in, const int* in_sizes, int n_in,
                              void* d_out, int out_size, void* d_ws, size_t ws_size,
                              hipStream_t stream) {
    const float* X1   = (const float*)d_in[0];
    const float* X2   = (const float*)d_in[2];
    const int*   src1 = (const int*)d_in[4];
    const int*   dst1 = (const int*)d_in[5];
    const int*   gid1 = (const int*)d_in[6];
    const int*   src2 = (const int*)d_in[7];
    const int*   dst2 = (const int*)d_in[8];
    const int*   gid2 = (const int*)d_in[9];
    const float* W1  = (const float*)d_in[10]; const float* b1  = (const float*)d_in[11];
    const float* Wr1 = (const float*)d_in[12]; const float* br1 = (const float*)d_in[13];
    const float* W2  = (const float*)d_in[14]; const float* b2  = (const float*)d_in[15];
    const float* Wr2 = (const float*)d_in[16]; const float* br2 = (const float*)d_in[17];
    const float* Ri1 = (const float*)d_in[18]; const float* rbi1 = (const float*)d_in[19];
    const float* Ro1 = (const float*)d_in[20]; const float* rbo1 = (const float*)d_in[21];
    const float* Ri2 = (const float*)d_in[22]; const float* rbi2 = (const float*)d_in[23];
    const float* Ro2 = (const float*)d_in[24]; const float* rbo2 = (const float*)d_in[25];
    const float* Wp  = (const float*)d_in[26]; const float* bp  = (const float*)d_in[27];

    // workspace layout (per-branch buffers; lifetime-disjoint aliases)
    const size_t NB = (size_t)NN * DD * sizeof(bf16);   // 25.6 MB
    char* p = (char*)d_ws;
    bf16* H1   = (bf16*)p; p += NB;     // H (agg->Ri)
    bf16* H2   = (bf16*)p; p += NB;
    bf16* hWR1 = (bf16*)p; p += NB;     // eb1 (CSR), then hW (fused->agg), then R (Ri->Ro)
    bf16* hWR2 = (bf16*)p; p += NB;
    bf16* res1 = (bf16*)p; p += NB;     // res (fused->agg)
    bf16* res2 = (bf16*)p; p += NB;
    float* G1  = (float*)p; p += (size_t)NG * GFEAT * sizeof(float);
    float* G2  = (float*)p; p += (size_t)NG * GFEAT * sizeof(float);
    // 8 weight mats; order: W1,Wr1,Ri1,Ro1,W2,Wr2,Ri2,Ro2 (W|Wr contiguous = fused Bt)
    bf16* Wbase = (bf16*)p; p += 8 * 65536 * sizeof(bf16);
    int* offs1 = (int*)p; p += (NN + 1) * sizeof(int);
    int* offs2 = (int*)p; p += (NN + 1) * sizeof(int);
    int* cnt1  = (int*)p; p += NBKT * NCHUNK * sizeof(int);
    int* cnt2  = (int*)p; p += NBKT * NCHUNK * sizeof(int);
    int* csr1  = (int*)p; p += NE * sizeof(int);
    int* csr2  = (int*)p; p += NE * sizeof(int);
    int2* eb1 = (int2*)hWR1;   // live only during CSR build (before fused writes hW)
    int2* eb2 = (int2*)hWR2;

    zero_g_kernel<<<dim3((NG * GFEAT + 255) / 256, 2), 256, 0, stream>>>(G1, G2);
    conv_w8_kernel<<<dim3(256, 8), 256, 0, stream>>>(W1, Wr1, Ri1, Ro1, W2, Wr2, Ri2, Ro2, Wbase);

    // CSR build (both branches): two-level counting sort, no global atomics
    csr_coarse_hist_kernel<<<dim3(NCHUNK, 2), 256, 0, stream>>>(dst1, dst2, cnt1, cnt2);
    csr_scan_kernel<<<dim3(1, 2), 1024, 0, stream>>>(cnt1, cnt2, offs1, offs2);
    csr_partition_kernel<<<dim3(NCHUNK, 2), 256, 0, stream>>>(
        src1, src2, dst1, dst2, cnt1, cnt2, eb1, eb2);
    csr_bucket_sort_kernel<<<dim3(NBKT, 2), 512, 0, stream>>>(
        cnt1, cnt2, eb1, eb2, offs1, offs2, csr1, csr2);

    // hW = X @ W ; res = relu(X @ Wr + br)   [conv fused into A-staging]
    mfma_gemm_fusedconv2_kernel<<<dim3(25 * 32, 2), 512, 0, stream>>>(
        X1, X2, Wbase + 0 * 65536, Wbase + 4 * 65536, br1, br2,
        hWR1, hWR2, res1, res2, NN);
    // H = relu(agg + b) + res
    agg_combine2_kernel<<<dim3((NN + 3) / 4, 2), 256, 0, stream>>>(
        hWR1, hWR2, csr1, csr2, offs1, offs2, b1, b2, res1, res2, H1, H2, NN);
    // R = relu(H @ Ri + rbi)
    mfma_gemm2_kernel<<<dim3(25 * 16, 2), 512, 0, stream>>>(
        H1, H2, Wbase + 2 * 65536, Wbase + 6 * 65536, rbi1, rbi2,
        hWR1, hWR2, NN, DD, 1);
    // G = segment_sum(R @ Ro + rbo) fused
    mfma_gemm_reduce2_kernel<<<dim3(25 * 16, 2), 512, 0, stream>>>(
        hWR1, hWR2, Wbase + 3 * 65536, Wbase + 7 * 65536, rbo1, rbo2,
        gid1, gid2, G1, G2, NN, GFEAT);

    predictor_kernel<<<(NG + 255) / 256, 256, 0, stream>>>(G1, G2, Wp, bp, (float*)d_out);
}